// Round 1
// baseline (2950.485 us; speedup 1.0000x reference)
//
#include <hip/hip_runtime.h>
#include <math.h>

#define NEGV -1000000000.0f
#define EPSV 1e-38f

typedef _Float16 h16;
typedef _Float16 h2 __attribute__((ext_vector_type(2)));

constexpr int ASTRIDE = 528 * 24;   // alpha floats per batch
constexpr int ETS = 584;            // et16/rw16 row stride in halves (1168 B, 16B aligned)
constexpr int TAS = 34;             // tA/tB row stride in halves (bank-spread)
constexpr int TCS = 24 * TAS;       // per-cell stride in tA/tB (816 halves)

__device__ __forceinline__ int tri(int i, int j) { return ((j * (j + 1)) >> 1) + i; }
__device__ __forceinline__ float la2(float a, float c) {
  float mx = fmaxf(a, c), mn = fminf(a, c);
  return mx + log1pf(__expf(mn - mx));
}
__device__ __forceinline__ float fdot2(h2 a, h2 b, float c) {
#if __has_builtin(__builtin_amdgcn_fdot2)
  return __builtin_amdgcn_fdot2(a, b, c, false);
#else
  return c + (float)a.x * (float)b.x + (float)a.y * (float)b.y;
#endif
}

//=====================================================================
// Kernel F: frontend (LN+MLP+log_softmax -> phi), theta softmax, alpha init.
// 512 blocks x 256 threads, one (b,t) per block.
//=====================================================================
__global__ void __launch_bounds__(256, 2) front_kernel(
    const float* __restrict__ g_seq, const float* __restrict__ Theta,
    const float* __restrict__ lng, const float* __restrict__ lnb,
    const float* __restrict__ W1, const float* __restrict__ bb1,
    const float* __restrict__ W2, const float* __restrict__ bb2,
    float* __restrict__ phi_g, float* __restrict__ et_g,
    float* __restrict__ aL_g) {
  __shared__ __align__(16) float wk[1200];
  const int tid = threadIdx.x;
  const int blk = blockIdx.x;
  {
    float* g = wk;                       // 512
    float2* red = (float2*)(wk + 512);   // 512
    float* hb = wk + 1024;               // 128
    float* ob = wk + 1152;               // 32
    float* sc = wk + 1184;               // 8
    float2 raw = ((const float2*)(g_seq + (size_t)blk * 512))[tid];
    red[tid] = make_float2(raw.x + raw.y, raw.x * raw.x + raw.y * raw.y);
    __syncthreads();
    if (tid < 128) { float2 o = red[tid + 128], m = red[tid]; red[tid] = make_float2(m.x + o.x, m.y + o.y); }
    __syncthreads();
    if (tid < 64) {
      float2 v = red[tid], o = red[tid + 64];
      v.x += o.x; v.y += o.y;
      for (int off = 32; off; off >>= 1) { v.x += __shfl_xor(v.x, off); v.y += __shfl_xor(v.y, off); }
      if (tid == 0) {
        float mu = v.x / 512.0f;
        float var = v.y / 512.0f - mu * mu;
        sc[0] = mu; sc[1] = rsqrtf(var + 1e-5f);
      }
    }
    __syncthreads();
    float mu = sc[0], rstd = sc[1];
    g[2 * tid]     = (raw.x - mu) * rstd * lng[2 * tid]     + lnb[2 * tid];
    g[2 * tid + 1] = (raw.y - mu) * rstd * lng[2 * tid + 1] + lnb[2 * tid + 1];
    __syncthreads();
    {
      int j = tid & 127, hh = tid >> 7, c0 = hh * 256;
      float a0 = 0, a1 = 0, a2 = 0, a3 = 0;
      for (int c = 0; c < 256; c += 4) {
        a0 = fmaf(g[c0 + c],     W1[(c0 + c) * 128 + j],     a0);
        a1 = fmaf(g[c0 + c + 1], W1[(c0 + c + 1) * 128 + j], a1);
        a2 = fmaf(g[c0 + c + 2], W1[(c0 + c + 2) * 128 + j], a2);
        a3 = fmaf(g[c0 + c + 3], W1[(c0 + c + 3) * 128 + j], a3);
      }
      ((float*)red)[tid] = (a0 + a1) + (a2 + a3);
    }
    __syncthreads();
    if (tid < 128) {
      float a = ((float*)red)[tid] + ((float*)red)[tid + 128] + bb1[tid];
      hb[tid] = 0.5f * a * (1.0f + erff(a * 0.70710678118654752f));
    }
    __syncthreads();
    if (tid < 192) {
      int n = tid >> 3, q = tid & 7;
      float a = 0;
      for (int k = 0; k < 16; k++) a = fmaf(hb[q * 16 + k], W2[(q * 16 + k) * 24 + n], a);
      ((float*)red)[tid] = a;
    }
    __syncthreads();
    if (tid < 24) {
      float a = bb2[tid];
      for (int q = 0; q < 8; q++) a += ((float*)red)[tid * 8 + q];
      ob[tid] = a;
    }
    __syncthreads();
    if (tid == 0) {
      float m = ob[0];
      for (int n = 1; n < 24; n++) m = fmaxf(m, ob[n]);
      float s = 0;
      for (int n = 0; n < 24; n++) s += __expf(ob[n] - m);
      sc[2] = m + __logf(s);
    }
    __syncthreads();
    if (tid < 24) phi_g[blk * 24 + tid] = ob[tid] - sc[2];
  }
  // theta softmax rows (576 rows of 24)
  if (tid < 64) {
    int z = tid & 31;
    bool up = tid >= 32;
    int row = up ? (512 + blk) : blk;
    bool valid = (!up) || (blk < 64);
    float v = (z < 24 && valid) ? Theta[row * 24 + z] : NEGV;
    float m = v;
    for (int off = 16; off; off >>= 1) m = fmaxf(m, __shfl_xor(m, off));
    float e = (z < 24 && valid) ? __expf(v - m) : 0.f;
    float s = e;
    for (int off = 16; off; off >>= 1) s += __shfl_xor(s, off);
    float lse = m + __logf(s);
    if (z < 24 && valid) et_g[row * 24 + z] = __expf(v - lse);
  }
  // alpha init (aL || aR contiguous), root aL[b][tri(0,31)*24+0] = 0
  for (int idx = blk * 256 + tid; idx < 2 * 16 * ASTRIDE; idx += 131072) {
    float v = NEGV;
    if (idx < 16 * ASTRIDE && (idx % ASTRIDE) == 11904) v = 0.f;
    aL_g[idx] = v;
  }
}

//=====================================================================
// Kernel A: per-batch inside+outside DP. 16 blocks x 1024 threads.
// beta + theta(fp16) + level-wide rr/w(fp16) resident in LDS; alpha in
// global (block-private, plain L1-cached loads/stores). All sync is
// __syncthreads().
//=====================================================================
__global__ void __launch_bounds__(1024, 4) pcfg_kernel(
    const float* __restrict__ phi_g, const float* __restrict__ et_g,
    float* __restrict__ aL_g, float* __restrict__ aR_g,
    float* __restrict__ p_nt_g, float* __restrict__ logZ_g) {
  __shared__ __align__(16) float smf[12672 + 256 + 256 + 32 + 744 + 16];
  __shared__ __align__(16) h16 smh[24 * ETS + 31 * ETS + 2 * 8 * TCS];
  float* beta = smf;            // 12672: beta[tri(i,j)*24 + n]
  float* mLs  = smf + 12672;    // 256 per-(cell,s): inside=pb(right max), outside=left max
  float* mRs  = smf + 12928;    // 256: outside right max
  float* Mc   = smf + 13184;    // 32 per-cell scale (inside M / outside ma)
  float* ea24 = smf + 13216;    // 744: outside exp(alpha-ma)
  float* miscf= smf + 13960;    // 16
  h16* et16 = smh;              // 24 rows x ETS: et16[x*ETS + y*24 + z]
  h16* rw16 = smh + 24 * ETS;   // 31 rows x ETS: rr (inside) / w (outside)
  h16* tA16 = smh + 24 * ETS + 31 * ETS;        // 8*TCS
  h16* tB16 = tA16 + 8 * TCS;                   // 8*TCS

  const int tid = threadIdx.x;
  const int b = blockIdx.x;
  float* aLb = aL_g + b * ASTRIDE;
  float* aRb = aR_g + b * ASTRIDE;

  // stage theta (fp32->fp16) and phi -> beta diagonal
  for (int i = tid; i < 13824; i += 1024) {
    int x = i / 576, f = i - x * 576;
    et16[x * ETS + f] = (h16)et_g[i];
  }
  for (int c = tid; c < 768; c += 1024) {
    int t = c / 24, n = c - t * 24;
    beta[tri(t, t) * 24 + n] = phi_g[b * 768 + c];
  }
  __syncthreads();

  //================ inside ================
  for (int l = 2; l <= 32; ++l) {
    const int S = l - 1, P = 33 - l;
    const int SPh = (S + 1) >> 1;
    for (int c0 = 0; c0 < P; c0 += 8) {
      const int CC = min(8, P - c0);
      // maxes per (cell,s) + per-cell M (shfl over the 32-lane cell group)
      if (tid < CC * 32) {
        int lc = tid >> 5, s = tid & 31;
        int cell = c0 + lc;
        float pa = NEGV, pb = NEGV;
        if (s < S) {
          const float4* bl4 = (const float4*)(beta + tri(cell, cell + s) * 24);
          const float4* br4 = (const float4*)(beta + tri(cell + s + 1, cell + S) * 24);
#pragma unroll
          for (int q = 0; q < 6; ++q) {
            float4 a = bl4[q], r = br4[q];
            pa = fmaxf(pa, fmaxf(fmaxf(a.x, a.y), fmaxf(a.z, a.w)));
            pb = fmaxf(pb, fmaxf(fmaxf(r.x, r.y), fmaxf(r.z, r.w)));
          }
          mLs[lc * S + s] = pb;
        }
        float v = (s < S) ? pa + pb : NEGV;
        for (int off = 16; off; off >>= 1) v = fmaxf(v, __shfl_xor(v, off));
        if (s == 0) Mc[cell] = v;
      }
      __syncthreads();
      // exp + transpose into tA/tB (fp16, s-contiguous for fdot2)
      for (int idx = tid; idx < CC * S * 24; idx += 1024) {
        int pair = idx / 24, y = idx - pair * 24;
        int lc = pair / S, s = pair - lc * S;
        int cell = c0 + lc;
        float m_ = mLs[lc * S + s], M = Mc[cell];
        float a = beta[tri(cell, cell + s) * 24 + y];
        float r = beta[tri(cell + s + 1, cell + S) * 24 + y];
        tA16[lc * TCS + y * TAS + s] = (h16)__expf(a + m_ - M);
        tB16[lc * TCS + y * TAS + s] = (h16)__expf(r - m_);
      }
      if ((S & 1) && tid < CC * 24) {  // zero-pad odd S for the fdot2 pair
        int lc = tid / 24, y = tid - lc * 24;
        tA16[lc * TCS + y * TAS + S] = (h16)0.f;
        tB16[lc * TCS + y * TAS + S] = (h16)0.f;
      }
      __syncthreads();
      // rank-1 accumulation: rr[cell][y][z] = sum_s eA[s][y]*eB[s][z]
      if (tid < CC * 36) {
        int lc = tid / 36, rem = tid - lc * 36, yq = rem / 6, zq = rem - yq * 6;
        int cell = c0 + lc;
        float acc[4][4] = {};
        const h16* ta = tA16 + lc * TCS + (4 * yq) * TAS;
        const h16* tb = tB16 + lc * TCS + (4 * zq) * TAS;
        for (int sp = 0; sp < SPh; ++sp) {
          h2 av[4], bv[4];
#pragma unroll
          for (int r = 0; r < 4; ++r) av[r] = *(const h2*)(ta + r * TAS + 2 * sp);
#pragma unroll
          for (int c = 0; c < 4; ++c) bv[c] = *(const h2*)(tb + c * TAS + 2 * sp);
#pragma unroll
          for (int r = 0; r < 4; ++r)
#pragma unroll
            for (int c = 0; c < 4; ++c) acc[r][c] = fdot2(av[r], bv[c], acc[r][c]);
        }
        h16* wr = rw16 + cell * ETS + (4 * yq) * 24 + 4 * zq;
#pragma unroll
        for (int r = 0; r < 4; ++r) {
          h2 p0; p0.x = (h16)acc[r][0]; p0.y = (h16)acc[r][1];
          h2 p1; p1.x = (h16)acc[r][2]; p1.y = (h16)acc[r][3];
          *(h2*)(wr + r * 24) = p0;
          *(h2*)(wr + r * 24 + 2) = p1;
        }
      }
      __syncthreads();
    }
    // whole-level matvec: beta[cell][x] = M + log( et[x][:] . rr[cell][:] )
    {
      int nq4 = (P + 3) >> 2;
      if (tid < nq4 * 96) {
        int kp = tid & 15, tile = tid >> 4;
        int xq = tile % 6, cq = tile / 6;
        float acc[16] = {};
        const h16* ep = et16 + kp * 36;
        const h16* rp = rw16 + kp * 36;
        for (int t = 0; t < 18; ++t) {
          h2 ev[4], rv[4];
#pragma unroll
          for (int r = 0; r < 4; ++r) ev[r] = *(const h2*)(ep + (xq + 6 * r) * ETS + 2 * t);
#pragma unroll
          for (int c = 0; c < 4; ++c) rv[c] = *(const h2*)(rp + (4 * cq + c) * ETS + 2 * t);
#pragma unroll
          for (int c = 0; c < 4; ++c)
#pragma unroll
            for (int r = 0; r < 4; ++r) acc[c * 4 + r] = fdot2(ev[r], rv[c], acc[c * 4 + r]);
        }
#pragma unroll
        for (int off = 1; off < 16; off <<= 1)
#pragma unroll
          for (int q = 0; q < 16; ++q) acc[q] += __shfl_xor(acc[q], off);
        int cc = kp >> 2, r = kp & 3;
        int cell = 4 * cq + cc, x = xq + 6 * r;
        if (cell < P)
          beta[tri(cell, cell + S) * 24 + x] = Mc[cell] + __logf(fmaxf(acc[kp], EPSV));
      }
      __syncthreads();
    }
  }
  if (tid == 0) {
    float z = beta[tri(0, 31) * 24];
    logZ_g[b] = z; miscf[0] = z;
  }
  __syncthreads();

  //================ outside ================
  for (int l = 32; l >= 2; --l) {
    const int S = l - 1, P = 33 - l;
    // O1: read alpha(cell), softmax-prep
    if (tid < P * 32) {
      int cell = tid >> 5, t = tid & 31;
      int base = tri(cell, cell + S) * 24;
      float av = NEGV;
      if (t < 24) av = la2(aLb[base + t], aRb[base + t]);
      float m = av;
      for (int off = 16; off; off >>= 1) m = fmaxf(m, __shfl_xor(m, off));
      if (t < 24) ea24[cell * 24 + t] = __expf(av - m);
      if (t == 0) Mc[cell] = m;
    }
    __syncthreads();
    // O2: w[cell][y][z] = sum_x ea24[cell][x] * et[x][y][z] (whole level)
    {
      int nq4 = (P + 3) >> 2;
      if (tid < nq4 * 72) {
        int cq = tid / 72, rem = tid - cq * 72, y = rem / 3, zo = rem - y * 3;
        float acc[4][8] = {};
        for (int x = 0; x < 24; ++x) {
          float4 ef = *(const float4*)(et16 + x * ETS + y * 24 + 8 * zo);
          const h16* eh = (const h16*)&ef;
          float ev[8];
#pragma unroll
          for (int k = 0; k < 8; ++k) ev[k] = (float)eh[k];
#pragma unroll
          for (int c = 0; c < 4; ++c) {
            int cell = 4 * cq + c;
            float a = (cell < P) ? ea24[cell * 24 + x] : 0.f;
#pragma unroll
            for (int k = 0; k < 8; ++k) acc[c][k] = fmaf(a, ev[k], acc[c][k]);
          }
        }
#pragma unroll
        for (int c = 0; c < 4; ++c) {
          int cell = 4 * cq + c;
          if (cell < P) {
            h16* wp = rw16 + cell * ETS + y * 24 + 8 * zo;
#pragma unroll
            for (int k = 0; k < 8; k += 2) {
              h2 pp; pp.x = (h16)acc[c][k]; pp.y = (h16)acc[c][k + 1];
              *(h2*)(wp + k) = pp;
            }
          }
        }
      }
      __syncthreads();
    }
    // chunks: beta maxes, exp, cL/cR contractions + alpha RMW
    for (int c0 = 0; c0 < P; c0 += 8) {
      const int CC = min(8, P - c0);
      if (tid < CC * 32) {
        int lc = tid >> 5, s = tid & 31;
        if (s < S) {
          int cell = c0 + lc;
          const float4* bl4 = (const float4*)(beta + tri(cell, cell + s) * 24);
          const float4* br4 = (const float4*)(beta + tri(cell + s + 1, cell + S) * 24);
          float pl = NEGV, pr = NEGV;
#pragma unroll
          for (int q = 0; q < 6; ++q) {
            float4 a = bl4[q], r = br4[q];
            pl = fmaxf(pl, fmaxf(fmaxf(a.x, a.y), fmaxf(a.z, a.w)));
            pr = fmaxf(pr, fmaxf(fmaxf(r.x, r.y), fmaxf(r.z, r.w)));
          }
          mLs[lc * S + s] = pl;
          mRs[lc * S + s] = pr;
        }
      }
      __syncthreads();
      // ebL/ebR (plain [pair][24] fp16 layout; k-contiguous for cL/cR)
      for (int idx = tid; idx < CC * S * 24; idx += 1024) {
        int pair = idx / 24, y = idx - pair * 24;
        int lc = pair / S, s = pair - lc * S;
        int cell = c0 + lc;
        tA16[pair * 24 + y] = (h16)__expf(beta[tri(cell, cell + s) * 24 + y] - mLs[pair]);
        tB16[pair * 24 + y] = (h16)__expf(beta[tri(cell + s + 1, cell + S) * 24 + y] - mRs[pair]);
      }
      __syncthreads();
      {
        int SPh2 = (S + 1) >> 1;
        int tot = CC * SPh2 * 6;
        // cL[s][y] = w[y][:] . ebR[s][:]  -> aL[tri(i,i+s)][y]
        for (int it = tid; it < tot; it += 1024) {
          int lc = it / (SPh2 * 6), rem = it - lc * (SPh2 * 6), sp = rem / 6, yq = rem - sp * 6;
          int cell = c0 + lc;
          int s0 = 2 * sp;
          float acc[2][4] = {};
          const h16* w0 = rw16 + cell * ETS + (4 * yq) * 24;
          const h16* r0 = tB16 + (lc * S + s0) * 24;
          const h16* r1 = r0 + 24;
          for (int zp = 0; zp < 12; ++zp) {
            h2 rb0 = *(const h2*)(r0 + 2 * zp);
            h2 rb1 = *(const h2*)(r1 + 2 * zp);
#pragma unroll
            for (int r = 0; r < 4; ++r) {
              h2 wv = *(const h2*)(w0 + r * 24 + 2 * zp);
              acc[0][r] = fdot2(wv, rb0, acc[0][r]);
              acc[1][r] = fdot2(wv, rb1, acc[1][r]);
            }
          }
          float ma = Mc[cell];
#pragma unroll
          for (int u = 0; u < 2; ++u) {
            int s = s0 + u;
            if (s < S) {
              float mrs = mRs[lc * S + s];
              float* tp = aLb + tri(cell, cell + s) * 24 + 4 * yq;
#pragma unroll
              for (int r = 0; r < 4; ++r) {
                float val = __logf(fmaxf(acc[u][r], EPSV)) + ma + mrs;
                tp[r] = la2(tp[r], val);
              }
            }
          }
        }
        // cR[s][z] = sum_y w[y][z]*ebL[s][y]  -> aR[tri(i+s+1,j)][z]
        for (int it = tid; it < tot; it += 1024) {
          int lc = it / (SPh2 * 6), rem = it - lc * (SPh2 * 6), sp = rem / 6, zq = rem - sp * 6;
          int cell = c0 + lc;
          int s0 = 2 * sp;
          float acc[2][4] = {};
          const h16* wq = rw16 + cell * ETS + 4 * zq;
          const h16* l0 = tA16 + (lc * S + s0) * 24;
          const h16* l1 = l0 + 24;
          for (int y = 0; y < 24; ++y) {
            h2 wv0 = *(const h2*)(wq + y * 24);
            h2 wv1 = *(const h2*)(wq + y * 24 + 2);
            float e0 = (float)l0[y], e1 = (float)l1[y];
            acc[0][0] = fmaf((float)wv0.x, e0, acc[0][0]);
            acc[0][1] = fmaf((float)wv0.y, e0, acc[0][1]);
            acc[0][2] = fmaf((float)wv1.x, e0, acc[0][2]);
            acc[0][3] = fmaf((float)wv1.y, e0, acc[0][3]);
            acc[1][0] = fmaf((float)wv0.x, e1, acc[1][0]);
            acc[1][1] = fmaf((float)wv0.y, e1, acc[1][1]);
            acc[1][2] = fmaf((float)wv1.x, e1, acc[1][2]);
            acc[1][3] = fmaf((float)wv1.y, e1, acc[1][3]);
          }
          float ma = Mc[cell];
#pragma unroll
          for (int u = 0; u < 2; ++u) {
            int s = s0 + u;
            if (s < S) {
              float mls = mLs[lc * S + s];
              float* tp = aRb + tri(cell + s + 1, cell + S) * 24 + 4 * zq;
#pragma unroll
              for (int r = 0; r < 4; ++r) {
                float val = __logf(fmaxf(acc[u][r], EPSV)) + ma + mls;
                tp[r] = la2(tp[r], val);
              }
            }
          }
        }
      }
      __syncthreads();
    }
  }

  // p_nt = exp(alpha_diag + beta_diag - logZ), layout [n*32 + t]
  {
    float logZv = miscf[0];
    for (int c = tid; c < 768; c += 1024) {
      int n = c >> 5, t = c & 31;
      int dA = tri(t, t) * 24 + n;
      float al = aLb[dA], ar = aRb[dA];
      p_nt_g[b * 768 + c] = __expf(la2(al, ar) + beta[tri(t, t) * 24 + n] - logZv);
    }
  }
}

//=====================================================================
// Kernel B: mask logits epilogue + loss. 512 blocks x 256 threads.
//=====================================================================
__global__ void __launch_bounds__(256, 2) mask_kernel(
    const float* __restrict__ vocab, const float* __restrict__ p_nt_g,
    const float* __restrict__ logZ_g, float* __restrict__ out) {
  __shared__ float p[768];
  const int tid = threadIdx.x;
  const int blk = blockIdx.x;
  const int b = blk & 15, local = blk >> 4;
  for (int c = tid; c < 768; c += 256) p[c] = p_nt_g[b * 768 + c];
  __syncthreads();
  int vbase = local * 1000;
  for (int pass = 0; pass < 2; pass++) {
    int o0 = tid + pass * 512, o1 = o0 + 256;
    bool v0ok = o0 < 1000, v1ok = o1 < 1000;
    int v0 = vbase + o0, v1 = vbase + o1;
    float vr0[24], vr1[24];
#pragma unroll
    for (int n = 0; n < 24; n++) {
      vr0[n] = v0ok ? vocab[n * 32000 + v0] : 0.f;
      vr1[n] = v1ok ? vocab[n * 32000 + v1] : 0.f;
    }
    float* ob0 = out + (size_t)b * 32 * 32000 + v0;
    float* ob1 = out + (size_t)b * 32 * 32000 + v1;
    for (int t4 = 0; t4 < 32; t4 += 4) {
      float a00 = 1e-6f, a01 = 1e-6f, a02 = 1e-6f, a03 = 1e-6f;
      float a10 = 1e-6f, a11 = 1e-6f, a12 = 1e-6f, a13 = 1e-6f;
#pragma unroll 6
      for (int n = 0; n < 24; n++) {
        float4 pv = *(const float4*)(p + n * 32 + t4);
        a00 = fmaf(pv.x, vr0[n], a00); a01 = fmaf(pv.y, vr0[n], a01);
        a02 = fmaf(pv.z, vr0[n], a02); a03 = fmaf(pv.w, vr0[n], a03);
        a10 = fmaf(pv.x, vr1[n], a10); a11 = fmaf(pv.y, vr1[n], a11);
        a12 = fmaf(pv.z, vr1[n], a12); a13 = fmaf(pv.w, vr1[n], a13);
      }
      if (v0ok) {
        ob0[(size_t)(t4 + 0) * 32000] = __logf(a00);
        ob0[(size_t)(t4 + 1) * 32000] = __logf(a01);
        ob0[(size_t)(t4 + 2) * 32000] = __logf(a02);
        ob0[(size_t)(t4 + 3) * 32000] = __logf(a03);
      }
      if (v1ok) {
        ob1[(size_t)(t4 + 0) * 32000] = __logf(a10);
        ob1[(size_t)(t4 + 1) * 32000] = __logf(a11);
        ob1[(size_t)(t4 + 2) * 32000] = __logf(a12);
        ob1[(size_t)(t4 + 3) * 32000] = __logf(a13);
      }
    }
  }
  if (blk == 0 && tid == 0) {
    float s = 0;
    for (int q = 0; q < 16; q++) s += logZ_g[q];
    out[16384000] = -s / 16.0f;
  }
}

// ---------------------------------------------------------------- launch
extern "C" void kernel_launch(void* const* d_in, const int* in_sizes, int n_in,
                              void* d_out, int out_size, void* d_ws, size_t ws_size,
                              hipStream_t stream) {
  (void)in_sizes; (void)n_in; (void)out_size; (void)ws_size;
  const float* g_seq = (const float*)d_in[0];
  const float* Theta = (const float*)d_in[1];
  const float* vocab = (const float*)d_in[2];
  const float* lng   = (const float*)d_in[3];
  const float* lnb   = (const float*)d_in[4];
  const float* W1    = (const float*)d_in[5];
  const float* bb1   = (const float*)d_in[6];
  const float* W2    = (const float*)d_in[7];
  const float* bb2   = (const float*)d_in[8];
  float* out = (float*)d_out;

  float* ws = (float*)d_ws;
  float* phi_g  = ws;                   // 512*24 = 12288
  float* et_g   = ws + 12288;           // 13824
  float* logZ_g = ws + 26112;           // 16
  float* p_nt_g = ws + 26128;           // 16*768 = 12288
  float* aL_g   = ws + 38416;           // 16*12672 = 202752
  float* aR_g   = aL_g + 16 * ASTRIDE;  // 202752

  void* fargs[] = {(void*)&g_seq, (void*)&Theta, (void*)&lng, (void*)&lnb,
                   (void*)&W1, (void*)&bb1, (void*)&W2, (void*)&bb2,
                   (void*)&phi_g, (void*)&et_g, (void*)&aL_g};
  hipLaunchKernel((const void*)front_kernel, dim3(512), dim3(256), fargs, 0, stream);

  void* aargs[] = {(void*)&phi_g, (void*)&et_g, (void*)&aL_g, (void*)&aR_g,
                   (void*)&p_nt_g, (void*)&logZ_g};
  hipLaunchKernel((const void*)pcfg_kernel, dim3(16), dim3(1024), aargs, 0, stream);

  void* bargs[] = {(void*)&vocab, (void*)&p_nt_g, (void*)&logZ_g, (void*)&out};
  hipLaunchKernel((const void*)mask_kernel, dim3(512), dim3(256), bargs, 0, stream);
}

// Round 2
// 495.067 us; speedup vs baseline: 5.9598x; 5.9598x over previous
//
#include <hip/hip_runtime.h>
#include <math.h>

#define NEGV -1000000000.0f
#define EPSV 1e-38f

constexpr int BSTRIDE = 528 * 32;   // beta floats per batch (128B-padded cells, write-once)
constexpr int ASTRIDE = 528 * 24;   // aL/aR floats per batch

__device__ __forceinline__ int tri(int i, int j) { return ((j * (j + 1)) >> 1) + i; }
__device__ __forceinline__ float la2(float a, float c) {
  float mx = fmaxf(a, c), mn = fminf(a, c);
  return mx + log1pf(__expf(mn - mx));
}
// relaxed agent-scope (sc1) ops — bypass L1/L2, hit the coherent point (r4-proven)
__device__ __forceinline__ void gstore(float* p, float v) {
  __hip_atomic_store(p, v, __ATOMIC_RELAXED, __HIP_MEMORY_SCOPE_AGENT);
}
__device__ __forceinline__ float gload(const float* p) {
  return __hip_atomic_load(p, __ATOMIC_RELAXED, __HIP_MEMORY_SCOPE_AGENT);
}
__device__ __forceinline__ void storeu(unsigned* p, unsigned v) {
  __hip_atomic_store(p, v, __ATOMIC_RELAXED, __HIP_MEMORY_SCOPE_AGENT);
}
__device__ __forceinline__ unsigned loadu(const unsigned* p) {
  return __hip_atomic_load(p, __ATOMIC_RELAXED, __HIP_MEMORY_SCOPE_AGENT);
}

// 512 blocks x 256 threads, cooperative. b = blk&15, local = blk>>4.
// Sync topology: per-level NEIGHBOR chain (not global barrier).
//   inside : block i, level l needs slotI[i+1] >= l-1   (right neighbor)
//   outside: block i, level l needs slotO[i-1] >= 32-l  (left neighbor)
// Transitive induction covers all deeper dependencies and serializes the
// alpha RMW writers (writer i2<i1 on a shared aR cell has always COMPLETED
// its level l1+(i1-i2) before i1 starts level l1).
__global__ void __launch_bounds__(256, 2) mega_kernel(
    const float* __restrict__ g_seq, const float* __restrict__ Theta,
    const float* __restrict__ vocab, const float* __restrict__ lng,
    const float* __restrict__ lnb, const float* __restrict__ W1,
    const float* __restrict__ bb1, const float* __restrict__ W2,
    const float* __restrict__ bb2, float* __restrict__ out,
    float* __restrict__ et_g, float* __restrict__ beta_g,
    float* __restrict__ aL_g, float* __restrict__ aR_g,
    unsigned* __restrict__ cnt, float* __restrict__ logZg) {
  __shared__ __align__(16) float sm[16160];
  float* etL = sm;          // 13824
  float* wk = sm + 13824;   // 2336
  const int tid = threadIdx.x;
  const int blk = blockIdx.x;
  const int b = blk & 15, local = blk >> 4;
  unsigned* gcnt  = cnt;                    // init stage-2 (16 arrivals)
  unsigned* done  = cnt + 8;                // logZ done count
  unsigned* ibc   = cnt + 16 + b * 16;      // init stage-1 per batch
  unsigned* slotI = cnt + 512 + b * 64;     // 32 inside progress words
  unsigned* slotO = slotI + 32;             // 32 outside progress words
  float* bbase = beta_g + b * BSTRIDE;
  float* aLb = aL_g + b * ASTRIDE;
  float* aRb = aR_g + b * ASTRIDE;

  //================ phase 0: frontend (task bt = blk) ================
  {
    float* g = wk;                       // 512
    float2* red = (float2*)(wk + 512);   // 512
    float* hb = wk + 1024;               // 128
    float* ob = wk + 1152;               // 32
    float* sc = wk + 1184;               // 8
    float2 raw = ((const float2*)(g_seq + (size_t)blk * 512))[tid];
    red[tid] = make_float2(raw.x + raw.y, raw.x * raw.x + raw.y * raw.y);
    __syncthreads();
    if (tid < 128) { float2 o = red[tid + 128], m = red[tid]; red[tid] = make_float2(m.x + o.x, m.y + o.y); }
    __syncthreads();
    if (tid < 64) {
      float2 v = red[tid], o = red[tid + 64];
      v.x += o.x; v.y += o.y;
      for (int off = 32; off; off >>= 1) { v.x += __shfl_xor(v.x, off); v.y += __shfl_xor(v.y, off); }
      if (tid == 0) {
        float mu = v.x / 512.0f;
        float var = v.y / 512.0f - mu * mu;
        sc[0] = mu; sc[1] = rsqrtf(var + 1e-5f);
      }
    }
    __syncthreads();
    float mu = sc[0], rstd = sc[1];
    g[2 * tid]     = (raw.x - mu) * rstd * lng[2 * tid]     + lnb[2 * tid];
    g[2 * tid + 1] = (raw.y - mu) * rstd * lng[2 * tid + 1] + lnb[2 * tid + 1];
    __syncthreads();
    {
      int j = tid & 127, hh = tid >> 7, c0 = hh * 256;
      float a0 = 0, a1 = 0, a2 = 0, a3 = 0;
      for (int c = 0; c < 256; c += 4) {
        a0 = fmaf(g[c0 + c],     W1[(c0 + c) * 128 + j],     a0);
        a1 = fmaf(g[c0 + c + 1], W1[(c0 + c + 1) * 128 + j], a1);
        a2 = fmaf(g[c0 + c + 2], W1[(c0 + c + 2) * 128 + j], a2);
        a3 = fmaf(g[c0 + c + 3], W1[(c0 + c + 3) * 128 + j], a3);
      }
      ((float*)red)[tid] = (a0 + a1) + (a2 + a3);
    }
    __syncthreads();
    if (tid < 128) {
      float a = ((float*)red)[tid] + ((float*)red)[tid + 128] + bb1[tid];
      hb[tid] = 0.5f * a * (1.0f + erff(a * 0.70710678118654752f));
    }
    __syncthreads();
    if (tid < 192) {
      int n = tid >> 3, q = tid & 7;
      float a = 0;
      for (int k = 0; k < 16; k++) a = fmaf(hb[q * 16 + k], W2[(q * 16 + k) * 24 + n], a);
      ((float*)red)[tid] = a;
    }
    __syncthreads();
    if (tid < 24) {
      float a = bb2[tid];
      for (int q = 0; q < 8; q++) a += ((float*)red)[tid * 8 + q];
      ob[tid] = a;
    }
    __syncthreads();
    if (tid == 0) {
      float m = ob[0];
      for (int n = 1; n < 24; n++) m = fmaxf(m, ob[n]);
      float s = 0;
      for (int n = 0; n < 24; n++) s += __expf(ob[n] - m);
      sc[2] = m + __logf(s);
    }
    __syncthreads();
    if (tid < 24) {
      int fb = blk >> 5, ft = blk & 31;
      gstore(beta_g + (size_t)fb * BSTRIDE + tri(ft, ft) * 32 + tid, ob[tid] - sc[2]);
    }
  }
  // theta rows (tm dropped — exact; et = exp(theta_log) <= 1)
  if (tid < 64) {
    int z = tid & 31;
    bool up = tid >= 32;
    int row = up ? (512 + blk) : blk;
    bool valid = (!up) || (blk < 64);
    float v = (z < 24 && valid) ? Theta[row * 24 + z] : NEGV;
    float m = v;
    for (int off = 16; off; off >>= 1) m = fmaxf(m, __shfl_xor(m, off));
    float e = (z < 24 && valid) ? __expf(v - m) : 0.f;
    float s = e;
    for (int off = 16; off; off >>= 1) s += __shfl_xor(s, off);
    float lse = m + __logf(s);
    if (z < 24 && valid) gstore(et_g + row * 24 + z, __expf(v - lse));
  }
  // alpha init (aL||aR contiguous); root aL[b][tri(0,31)][0] = 0 folded in
  for (int idx = blk * 256 + tid; idx < 2 * 16 * ASTRIDE; idx += 131072) {
    float v = NEGV;
    if (idx < 16 * ASTRIDE && (idx % ASTRIDE) == 11904) v = 0.f;
    gstore(aL_g + idx, v);
  }
  // ---- init global barrier (two-stage, r4-proven) ----
  __builtin_amdgcn_s_waitcnt(0);
  __syncthreads();
  if (tid == 0) {
    __hip_atomic_fetch_add(ibc, 1u, __ATOMIC_RELAXED, __HIP_MEMORY_SCOPE_AGENT);
    if (local == 0) {
      while (loadu(ibc) < 32u) __builtin_amdgcn_s_sleep(2);
      __hip_atomic_fetch_add(gcnt, 1u, __ATOMIC_RELAXED, __HIP_MEMORY_SCOPE_AGENT);
    }
    while (loadu(gcnt) < 16u) __builtin_amdgcn_s_sleep(2);
  }
  __syncthreads();

  // stage et into LDS once (write-once region; plain vectorized loads safe)
  for (int i4 = tid; i4 < 3456; i4 += 256)
    ((float4*)etL)[i4] = ((const float4*)et_g)[i4];
  __syncthreads();

  //================ inside: levels 2..32-local, neighbor-gated ================
  {
    float* eA = wk;           // 744
    float* eB = wk + 744;     // 744
    float* rr = wk + 1488;    // 576
    float* red2 = wk + 2064;  // 192
    float* mrl = wk + 2256;   // 32
    float* msm = wk + 2288;   // 32
    float* scal = wk + 2320;  // 16
    const int lastLI = 32 - local;   // local=31 -> loop skipped
    for (int l = 2; l <= lastLI; l++) {
      int S = l - 1;
      // gate: right neighbor done with level l-1 (l=2 covered by init barrier)
      if (l >= 3 && tid == 0) {
        unsigned need = (unsigned)(l - 1);
        while (loadu(slotI + local + 1) < need) __builtin_amdgcn_s_sleep(1);
      }
      __syncthreads();
      {
        int i = local, j = i + S, SN = S * 24;
        for (int idx4 = tid; idx4 < 6 * S; idx4 += 256) {
          int s = idx4 / 6, q = idx4 - 6 * s;
          ((float4*)eA)[idx4] = ((const float4*)(bbase + (size_t)tri(i, i + s) * 32))[q];
          ((float4*)eB)[idx4] = ((const float4*)(bbase + (size_t)tri(i + s + 1, j) * 32))[q];
        }
        __syncthreads();
        if (tid < 8 * S) {
          int s = tid >> 3, q = tid & 7, y0 = q * 3;
          float pa = fmaxf(fmaxf(eA[s * 24 + y0], eA[s * 24 + y0 + 1]), eA[s * 24 + y0 + 2]);
          float pb = fmaxf(fmaxf(eB[s * 24 + y0], eB[s * 24 + y0 + 1]), eB[s * 24 + y0 + 2]);
          for (int off = 4; off; off >>= 1) {
            pa = fmaxf(pa, __shfl_xor(pa, off));
            pb = fmaxf(pb, __shfl_xor(pb, off));
          }
          if (q == 0) { mrl[s] = pb; msm[s] = pa + pb; }
        }
        __syncthreads();
        if (tid < 32) {
          float v = (tid < S) ? msm[tid] : NEGV;
          for (int off = 16; off; off >>= 1) v = fmaxf(v, __shfl_xor(v, off));
          if (tid == 0) scal[0] = v;
        }
        __syncthreads();
        float M = scal[0];
        for (int idx = tid; idx < SN; idx += 256) {
          int s = idx / 24;
          float m_ = mrl[s];
          eA[idx] = __expf(eA[idx] + m_ - M);
          eB[idx] = __expf(eB[idx] - m_);
        }
        __syncthreads();
        if (tid < 144) {
          int y = tid / 6, zq = tid % 6;
          float4 acc = make_float4(0, 0, 0, 0);
          for (int s = 0; s < S; s++) {
            float a = eA[s * 24 + y];
            float4 b4 = ((float4*)eB)[s * 6 + zq];
            acc.x = fmaf(a, b4.x, acc.x); acc.y = fmaf(a, b4.y, acc.y);
            acc.z = fmaf(a, b4.z, acc.z); acc.w = fmaf(a, b4.w, acc.w);
          }
          ((float4*)rr)[y * 6 + zq] = acc;
        }
        __syncthreads();
        if (tid < 192) {
          int x = tid >> 3, c = tid & 7;
          const float4* e4 = (const float4*)(etL + x * 576 + c * 72);
          const float4* r4 = (const float4*)(rr + c * 72);
          float a0 = 0, a1 = 0;
#pragma unroll
          for (int q = 0; q < 18; q += 2) {
            float4 ev = e4[q], rv = r4[q];
            a0 = fmaf(ev.x, rv.x, fmaf(ev.y, rv.y, fmaf(ev.z, rv.z, fmaf(ev.w, rv.w, a0))));
            float4 e2 = e4[q + 1], r2 = r4[q + 1];
            a1 = fmaf(e2.x, r2.x, fmaf(e2.y, r2.y, fmaf(e2.z, r2.z, fmaf(e2.w, r2.w, a1))));
          }
          red2[tid] = a0 + a1;
        }
        __syncthreads();
        if (tid < 24) {
          float a = 0;
          for (int q = 0; q < 8; q++) a += red2[tid * 8 + q];
          gstore(bbase + (size_t)tri(i, j) * 32 + tid, M + __logf(fmaxf(a, EPSV)));
        }
      }
      // ---- drain + post own progress ----
      __builtin_amdgcn_s_waitcnt(0);
      __syncthreads();
      if (tid == 0) storeu(slotI + local, (unsigned)l);
    }
  }
  if (local == 0 && tid == 0) {
    gstore(logZg + b, gload(bbase + 496 * 32));
    __hip_atomic_fetch_add(done, 1u, __ATOMIC_RELAXED, __HIP_MEMORY_SCOPE_AGENT);
  }

  //================ outside: levels 32-local..2, neighbor-gated ================
  {
    float* w = wk;            // 576
    float* ebL = wk + 576;    // 744
    float* ebR = wk + 1320;   // 744
    float* mLs = wk + 2064;   // 32
    float* mRs = wk + 2096;   // 32
    float* ea24 = wk + 2128;  // 24
    float* scal = wk + 2320;  // 16
    const int lastLO = 32 - local;   // first (longest-span) outside level
    for (int l = lastLO; l >= 2; l--) {
      int S = l - 1;
      // gate: left neighbor done with level l+1
      if (local > 0 && tid == 0) {
        unsigned need = (unsigned)(32 - l);
        while (loadu(slotO + local - 1) < need) __builtin_amdgcn_s_sleep(1);
      }
      __syncthreads();
      {
        int i = local, j = i + S, SN = S * 24;
        if (tid < 32) {
          float av = NEGV;
          if (tid < 24) av = la2(gload(aLb + tri(i, j) * 24 + tid), gload(aRb + tri(i, j) * 24 + tid));
          float m = av;
          for (int off = 16; off; off >>= 1) m = fmaxf(m, __shfl_xor(m, off));
          if (tid < 24) ea24[tid] = __expf(av - m);
          if (tid == 0) scal[0] = m;
        }
        __syncthreads();
        float ma = scal[0];
        if (tid < 144) {
          int y = tid / 6, zq = tid % 6;
          float4 acc = make_float4(0, 0, 0, 0);
#pragma unroll 4
          for (int x = 0; x < 24; x++) {
            float a = ea24[x];
            float4 ev = ((const float4*)(etL + x * 576 + y * 24))[zq];
            acc.x = fmaf(a, ev.x, acc.x); acc.y = fmaf(a, ev.y, acc.y);
            acc.z = fmaf(a, ev.z, acc.z); acc.w = fmaf(a, ev.w, acc.w);
          }
          ((float4*)w)[y * 6 + zq] = acc;
        }
        for (int idx4 = tid; idx4 < 6 * S; idx4 += 256) {
          int s = idx4 / 6, q = idx4 - 6 * s;
          ((float4*)ebL)[idx4] = ((const float4*)(bbase + (size_t)tri(i, i + s) * 32))[q];
          ((float4*)ebR)[idx4] = ((const float4*)(bbase + (size_t)tri(i + s + 1, j) * 32))[q];
        }
        __syncthreads();
        if (tid < 8 * S) {
          int s = tid >> 3, q = tid & 7, y0 = q * 3;
          float pl = fmaxf(fmaxf(ebL[s * 24 + y0], ebL[s * 24 + y0 + 1]), ebL[s * 24 + y0 + 2]);
          float pr = fmaxf(fmaxf(ebR[s * 24 + y0], ebR[s * 24 + y0 + 1]), ebR[s * 24 + y0 + 2]);
          for (int off = 4; off; off >>= 1) {
            pl = fmaxf(pl, __shfl_xor(pl, off));
            pr = fmaxf(pr, __shfl_xor(pr, off));
          }
          if (q == 0) { mLs[s] = pl; mRs[s] = pr; }
        }
        __syncthreads();
        for (int idx = tid; idx < SN; idx += 256) {
          int s = idx / 24;
          ebL[idx] = __expf(ebL[idx] - mLs[s]);
          ebR[idx] = __expf(ebR[idx] - mRs[s]);
        }
        __syncthreads();
        for (int u = tid; u < 2 * SN; u += 256) {
          if (u < SN) {  // cL -> aL[tri(i,i+s)][y]; unique writer per level
            int s = u / 24, y = u - s * 24;
            const float4* w4 = (const float4*)(w + y * 24);
            const float4* r4 = (const float4*)(ebR + s * 24);
            float acc = 0;
#pragma unroll
            for (int q = 0; q < 6; q++) {
              float4 a = w4[q], c4 = r4[q];
              acc = fmaf(a.x, c4.x, fmaf(a.y, c4.y, fmaf(a.z, c4.z, fmaf(a.w, c4.w, acc))));
            }
            float val = __logf(fmaxf(acc, EPSV)) + ma + mRs[s];
            float* t = aLb + tri(i, i + s) * 24 + y;
            gstore(t, la2(gload(t), val));
          } else {       // cR -> aR[tri(i+s+1,j)][z]
            int u2 = u - SN;
            int s = u2 / 24, z = u2 - s * 24;
            float acc = 0;
            for (int y = 0; y < 24; y++) acc = fmaf(w[y * 24 + z], ebL[s * 24 + y], acc);
            float val = __logf(fmaxf(acc, EPSV)) + ma + mLs[s];
            float* t = aRb + tri(i + s + 1, j) * 24 + z;
            gstore(t, la2(gload(t), val));
          }
        }
      }
      // ---- drain + post own progress ----
      __builtin_amdgcn_s_waitcnt(0);
      __syncthreads();
      if (tid == 0) storeu(slotO + local, (unsigned)(33 - l));
    }
  }
  // ---- mask gate: all outside of batch b finished (slotO[0..30] == 31) ----
  if (tid < 64) {
    for (;;) {
      unsigned v = 31;
      if (tid < 31) v = loadu(slotO + tid);
      if (__ballot(v >= 31u) == ~0ull) break;
      __builtin_amdgcn_s_sleep(1);
    }
  }
  __syncthreads();

  //================ mask logits + loss ================
  {
    float* p = wk;  // 768, layout [n*32 + t]
    float logZv = gload(bbase + 496 * 32);
    for (int c = tid; c < 768; c += 256) {
      int n = c >> 5, t = c & 31;
      int dA = tri(t, t) * 24 + n;
      float al = gload(aLb + dA), ar = gload(aRb + dA);
      p[c] = __expf(la2(al, ar) + bbase[(size_t)tri(t, t) * 32 + n] - logZv);
    }
    __syncthreads();
    int vbase = local * 1000;
    for (int pass = 0; pass < 2; pass++) {
      int o0 = tid + pass * 512, o1 = o0 + 256;
      bool v0ok = o0 < 1000, v1ok = o1 < 1000;
      int v0 = vbase + o0, v1 = vbase + o1;
      float vr0[24], vr1[24];
#pragma unroll
      for (int n = 0; n < 24; n++) {
        vr0[n] = v0ok ? vocab[n * 32000 + v0] : 0.f;
        vr1[n] = v1ok ? vocab[n * 32000 + v1] : 0.f;
      }
      float* ob0 = out + (size_t)b * 32 * 32000 + v0;
      float* ob1 = out + (size_t)b * 32 * 32000 + v1;
      for (int t4 = 0; t4 < 32; t4 += 4) {
        float a00 = 1e-6f, a01 = 1e-6f, a02 = 1e-6f, a03 = 1e-6f;
        float a10 = 1e-6f, a11 = 1e-6f, a12 = 1e-6f, a13 = 1e-6f;
#pragma unroll 6
        for (int n = 0; n < 24; n++) {
          float4 pv = *(const float4*)(p + n * 32 + t4);
          a00 = fmaf(pv.x, vr0[n], a00); a01 = fmaf(pv.y, vr0[n], a01);
          a02 = fmaf(pv.z, vr0[n], a02); a03 = fmaf(pv.w, vr0[n], a03);
          a10 = fmaf(pv.x, vr1[n], a10); a11 = fmaf(pv.y, vr1[n], a11);
          a12 = fmaf(pv.z, vr1[n], a12); a13 = fmaf(pv.w, vr1[n], a13);
        }
        if (v0ok) {
          ob0[(size_t)(t4 + 0) * 32000] = __logf(a00);
          ob0[(size_t)(t4 + 1) * 32000] = __logf(a01);
          ob0[(size_t)(t4 + 2) * 32000] = __logf(a02);
          ob0[(size_t)(t4 + 3) * 32000] = __logf(a03);
        }
        if (v1ok) {
          ob1[(size_t)(t4 + 0) * 32000] = __logf(a10);
          ob1[(size_t)(t4 + 1) * 32000] = __logf(a11);
          ob1[(size_t)(t4 + 2) * 32000] = __logf(a12);
          ob1[(size_t)(t4 + 3) * 32000] = __logf(a13);
        }
      }
    }
    if (blk == 0 && tid == 0) {
      while (loadu(done) < 16u) __builtin_amdgcn_s_sleep(2);
      float s = 0;
      for (int q = 0; q < 16; q++) s += gload(logZg + q);
      out[16384000] = -s / 16.0f;
    }
  }
}

// ---------------------------------------------------------------- launch
extern "C" void kernel_launch(void* const* d_in, const int* in_sizes, int n_in,
                              void* d_out, int out_size, void* d_ws, size_t ws_size,
                              hipStream_t stream) {
  (void)in_sizes; (void)n_in; (void)out_size; (void)ws_size;
  const float* g_seq = (const float*)d_in[0];
  const float* Theta = (const float*)d_in[1];
  const float* vocab = (const float*)d_in[2];
  const float* lng   = (const float*)d_in[3];
  const float* lnb   = (const float*)d_in[4];
  const float* W1    = (const float*)d_in[5];
  const float* bb1   = (const float*)d_in[6];
  const float* W2    = (const float*)d_in[7];
  const float* bb2   = (const float*)d_in[8];
  float* out = (float*)d_out;

  float* ws = (float*)d_ws;
  unsigned* cnt = (unsigned*)d_ws;            // ws[0..2048) counters (memset 0)
  float* logZg  = ws + 2048;                  // 16
  float* et_g   = ws + 4096;                  // 13824
  float* beta_g = ws + 18432;                 // 16 * 16896 = 270336
  float* aL_g   = beta_g + 16 * BSTRIDE;      // 202752
  float* aR_g   = aL_g + 16 * ASTRIDE;        // 202752

  hipMemsetAsync(d_ws, 0, 8192, stream);

  void* args[] = {(void*)&g_seq, (void*)&Theta, (void*)&vocab, (void*)&lng,
                  (void*)&lnb, (void*)&W1, (void*)&bb1, (void*)&W2, (void*)&bb2,
                  (void*)&out, (void*)&et_g, (void*)&beta_g, (void*)&aL_g,
                  (void*)&aR_g, (void*)&cnt, (void*)&logZg};
  hipLaunchCooperativeKernel((const void*)mega_kernel, dim3(512), dim3(256),
                             args, 0, stream);
}

// Round 5
// 479.587 us; speedup vs baseline: 6.1521x; 1.0323x over previous
//
#include <hip/hip_runtime.h>
#include <math.h>

#define NEGV -1000000000.0f
#define EPSV 1e-38f

typedef _Float16 h16;
typedef _Float16 h2 __attribute__((ext_vector_type(2)));
typedef _Float16 h4 __attribute__((ext_vector_type(4)));

constexpr int BSTRIDE = 528 * 32;   // beta floats per batch (128B-padded cells, write-once)
constexpr int ASTRIDE = 528 * 24;   // aL/aR floats per batch

// LDS layout (bytes from smem base); total 37744
constexpr int O_WK   = 28032;  // et16h: 24 x 584 halves = 28032 B
constexpr int O_EA   = 28032;  // eA / ebL: 744 f
constexpr int O_EBF  = 31008;  // eBf / ebRf: 744 f (raw right child)
constexpr int O_EB16 = 33984;  // exp'd right child: 744 h
constexpr int O_RR   = 35472;  // rr / w: 576 h (+pad)
constexpr int O_RED2 = 36656;  // red2: 192 f / ea24: 24 f
constexpr int O_MRL  = 37424;  // 32 f
constexpr int O_MSM  = 37552;  // 32 f
constexpr int O_SCAL = 37680;  // 16 f
constexpr int SMEM_SZ = 37744;

__device__ __forceinline__ int tri(int i, int j) { return ((j * (j + 1)) >> 1) + i; }
__device__ __forceinline__ float la2(float a, float c) {
  float mx = fmaxf(a, c), mn = fminf(a, c);
  return mx + log1pf(__expf(mn - mx));
}
// relaxed agent-scope ops — bypass L1/L2, hit the coherent point (r0/r2-proven)
__device__ __forceinline__ void gstore(float* p, float v) {
  __hip_atomic_store(p, v, __ATOMIC_RELAXED, __HIP_MEMORY_SCOPE_AGENT);
}
__device__ __forceinline__ float gload(const float* p) {
  return __hip_atomic_load(p, __ATOMIC_RELAXED, __HIP_MEMORY_SCOPE_AGENT);
}
__device__ __forceinline__ void storeu(unsigned* p, unsigned v) {
  __hip_atomic_store(p, v, __ATOMIC_RELAXED, __HIP_MEMORY_SCOPE_AGENT);
}
__device__ __forceinline__ unsigned loadu(const unsigned* p) {
  return __hip_atomic_load(p, __ATOMIC_RELAXED, __HIP_MEMORY_SCOPE_AGENT);
}
__device__ __forceinline__ float d2(h16 ax, h16 ay, h16 bx, h16 by, float c) {
#if __has_builtin(__builtin_amdgcn_fdot2)
  h2 a; a.x = ax; a.y = ay;
  h2 b; b.x = bx; b.y = by;
  return __builtin_amdgcn_fdot2(a, b, c, false);
#else
  return c + (float)ax * (float)bx + (float)ay * (float)by;
#endif
}

// 512 blocks x 256 threads, cooperative. b = blk&15, local = blk>>4.
// Sync topology: per-level NEIGHBOR chain (r2-proven):
//   inside : block i, level l needs slotI[i+1] >= l-1   (right neighbor)
//   outside: block i, level l needs slotO[i-1] >= 32-l  (left neighbor)
__global__ void __launch_bounds__(256, 2) mega_kernel(
    const float* __restrict__ g_seq, const float* __restrict__ Theta,
    const float* __restrict__ vocab, const float* __restrict__ lng,
    const float* __restrict__ lnb, const float* __restrict__ W1,
    const float* __restrict__ bb1, const float* __restrict__ W2,
    const float* __restrict__ bb2, float* __restrict__ out,
    float* __restrict__ et_g, float* __restrict__ beta_g,
    float* __restrict__ aL_g, float* __restrict__ aR_g,
    unsigned* __restrict__ cnt, float* __restrict__ logZg) {
  __shared__ __align__(16) unsigned char smem[SMEM_SZ];
  h16* et16h = (h16*)smem;              // 24 x 584 halves
  float* wk = (float*)(smem + O_WK);    // frontend scratch (1192 f)
  const int tid = threadIdx.x;
  const int blk = blockIdx.x;
  const int b = blk & 15, local = blk >> 4;
  unsigned* gcnt  = cnt;                    // init stage-2 (16 arrivals)
  unsigned* done  = cnt + 8;                // logZ done count
  unsigned* ibc   = cnt + 16 + b * 16;      // init stage-1 per batch
  unsigned* slotI = cnt + 512 + b * 64;     // 32 inside progress words
  unsigned* slotO = slotI + 32;             // 32 outside progress words
  float* bbase = beta_g + b * BSTRIDE;
  float* aLb = aL_g + b * ASTRIDE;
  float* aRb = aR_g + b * ASTRIDE;

  //================ phase 0: frontend (task bt = blk) ================
  {
    float* g = wk;                       // 512
    float2* red = (float2*)(wk + 512);   // 512
    float* hb = wk + 1024;               // 128
    float* ob = wk + 1152;               // 32
    float* sc = wk + 1184;               // 8
    float2 raw = ((const float2*)(g_seq + (size_t)blk * 512))[tid];
    red[tid] = make_float2(raw.x + raw.y, raw.x * raw.x + raw.y * raw.y);
    __syncthreads();
    if (tid < 128) { float2 o = red[tid + 128], m = red[tid]; red[tid] = make_float2(m.x + o.x, m.y + o.y); }
    __syncthreads();
    if (tid < 64) {
      float2 v = red[tid], o = red[tid + 64];
      v.x += o.x; v.y += o.y;
      for (int off = 32; off; off >>= 1) { v.x += __shfl_xor(v.x, off); v.y += __shfl_xor(v.y, off); }
      if (tid == 0) {
        float mu = v.x / 512.0f;
        float var = v.y / 512.0f - mu * mu;
        sc[0] = mu; sc[1] = rsqrtf(var + 1e-5f);
      }
    }
    __syncthreads();
    float mu = sc[0], rstd = sc[1];
    g[2 * tid]     = (raw.x - mu) * rstd * lng[2 * tid]     + lnb[2 * tid];
    g[2 * tid + 1] = (raw.y - mu) * rstd * lng[2 * tid + 1] + lnb[2 * tid + 1];
    __syncthreads();
    {
      int j = tid & 127, hh = tid >> 7, c0 = hh * 256;
      float a0 = 0, a1 = 0, a2 = 0, a3 = 0;
      for (int c = 0; c < 256; c += 4) {
        a0 = fmaf(g[c0 + c],     W1[(c0 + c) * 128 + j],     a0);
        a1 = fmaf(g[c0 + c + 1], W1[(c0 + c + 1) * 128 + j], a1);
        a2 = fmaf(g[c0 + c + 2], W1[(c0 + c + 2) * 128 + j], a2);
        a3 = fmaf(g[c0 + c + 3], W1[(c0 + c + 3) * 128 + j], a3);
      }
      ((float*)red)[tid] = (a0 + a1) + (a2 + a3);
    }
    __syncthreads();
    if (tid < 128) {
      float a = ((float*)red)[tid] + ((float*)red)[tid + 128] + bb1[tid];
      hb[tid] = 0.5f * a * (1.0f + erff(a * 0.70710678118654752f));
    }
    __syncthreads();
    if (tid < 192) {
      int n = tid >> 3, q = tid & 7;
      float a = 0;
      for (int k = 0; k < 16; k++) a = fmaf(hb[q * 16 + k], W2[(q * 16 + k) * 24 + n], a);
      ((float*)red)[tid] = a;
    }
    __syncthreads();
    if (tid < 24) {
      float a = bb2[tid];
      for (int q = 0; q < 8; q++) a += ((float*)red)[tid * 8 + q];
      ob[tid] = a;
    }
    __syncthreads();
    if (tid == 0) {
      float m = ob[0];
      for (int n = 1; n < 24; n++) m = fmaxf(m, ob[n]);
      float s = 0;
      for (int n = 0; n < 24; n++) s += __expf(ob[n] - m);
      sc[2] = m + __logf(s);
    }
    __syncthreads();
    if (tid < 24) {
      int fb = blk >> 5, ft = blk & 31;
      gstore(beta_g + (size_t)fb * BSTRIDE + tri(ft, ft) * 32 + tid, ob[tid] - sc[2]);
    }
  }
  // theta rows (tm dropped — exact; et = exp(theta_log) <= 1)
  if (tid < 64) {
    int z = tid & 31;
    bool up = tid >= 32;
    int row = up ? (512 + blk) : blk;
    bool valid = (!up) || (blk < 64);
    float v = (z < 24 && valid) ? Theta[row * 24 + z] : NEGV;
    float m = v;
    for (int off = 16; off; off >>= 1) m = fmaxf(m, __shfl_xor(m, off));
    float e = (z < 24 && valid) ? __expf(v - m) : 0.f;
    float s = e;
    for (int off = 16; off; off >>= 1) s += __shfl_xor(s, off);
    float lse = m + __logf(s);
    if (z < 24 && valid) gstore(et_g + row * 24 + z, __expf(v - lse));
  }
  // alpha init (aL||aR contiguous); root aL[b][tri(0,31)][0] = 0 folded in
  for (int idx = blk * 256 + tid; idx < 2 * 16 * ASTRIDE; idx += 131072) {
    float v = NEGV;
    if (idx < 16 * ASTRIDE && (idx % ASTRIDE) == 11904) v = 0.f;
    gstore(aL_g + idx, v);
  }
  // ---- init global barrier (two-stage, r2-proven) ----
  __builtin_amdgcn_s_waitcnt(0);
  __syncthreads();
  if (tid == 0) {
    __hip_atomic_fetch_add(ibc, 1u, __ATOMIC_RELAXED, __HIP_MEMORY_SCOPE_AGENT);
    if (local == 0) {
      while (loadu(ibc) < 32u) __builtin_amdgcn_s_sleep(2);
      __hip_atomic_fetch_add(gcnt, 1u, __ATOMIC_RELAXED, __HIP_MEMORY_SCOPE_AGENT);
    }
    while (loadu(gcnt) < 16u) __builtin_amdgcn_s_sleep(2);
  }
  __syncthreads();

  // stage et into LDS as fp16, row stride 584 halves (bank-spread; write-once
  // region so plain vectorized loads are safe — values identical every launch)
  for (int i4 = tid; i4 < 3456; i4 += 256) {
    int f = i4 * 4;
    int x = f / 576, r = f - x * 576;
    float4 v = ((const float4*)et_g)[i4];
    h4 t; t.x = (h16)v.x; t.y = (h16)v.y; t.z = (h16)v.z; t.w = (h16)v.w;
    *(h4*)(et16h + x * 584 + r) = t;
  }
  __syncthreads();

  //================ inside: levels 2..32-local, neighbor-gated ================
  {
    float* eA   = (float*)(smem + O_EA);    // 744 f (left; exp'd in place)
    float* eBf  = (float*)(smem + O_EBF);   // 744 f (right, raw)
    h16*  eb16  = (h16*)(smem + O_EB16);    // 744 h (right, exp'd fp16)
    h16*  rrh   = (h16*)(smem + O_RR);      // 576 h
    float* red2 = (float*)(smem + O_RED2);  // 192 f
    float* mrl  = (float*)(smem + O_MRL);   // 32
    float* msm  = (float*)(smem + O_MSM);   // 32
    float* scal = (float*)(smem + O_SCAL);  // 16
    const int lastLI = 32 - local;   // local=31 -> loop skipped
    for (int l = 2; l <= lastLI; l++) {
      int S = l - 1;
      // gate: right neighbor done with level l-1 (l=2 covered by init barrier)
      if (l >= 3 && tid == 0) {
        unsigned need = (unsigned)(l - 1);
        while (loadu(slotI + local + 1) < need) __builtin_amdgcn_s_sleep(1);
      }
      __syncthreads();
      {
        int i = local, j = i + S, SN = S * 24;
        for (int idx4 = tid; idx4 < 6 * S; idx4 += 256) {
          int s = idx4 / 6, q = idx4 - 6 * s;
          ((float4*)eA)[idx4]  = ((const float4*)(bbase + (size_t)tri(i, i + s) * 32))[q];
          ((float4*)eBf)[idx4] = ((const float4*)(bbase + (size_t)tri(i + s + 1, j) * 32))[q];
        }
        __syncthreads();
        if (tid < 8 * S) {
          int s = tid >> 3, q = tid & 7, y0 = q * 3;
          float pa = fmaxf(fmaxf(eA[s * 24 + y0], eA[s * 24 + y0 + 1]), eA[s * 24 + y0 + 2]);
          float pb = fmaxf(fmaxf(eBf[s * 24 + y0], eBf[s * 24 + y0 + 1]), eBf[s * 24 + y0 + 2]);
          for (int off = 4; off; off >>= 1) {
            pa = fmaxf(pa, __shfl_xor(pa, off));
            pb = fmaxf(pb, __shfl_xor(pb, off));
          }
          if (q == 0) { mrl[s] = pb; msm[s] = pa + pb; }
        }
        __syncthreads();
        if (tid < 32) {
          float v = (tid < S) ? msm[tid] : NEGV;
          for (int off = 16; off; off >>= 1) v = fmaxf(v, __shfl_xor(v, off));
          if (tid == 0) scal[0] = v;
        }
        __syncthreads();
        float M = scal[0];
        for (int idx = tid; idx < SN; idx += 256) {
          int s = idx / 24;
          float m_ = mrl[s];
          eA[idx] = __expf(eA[idx] + m_ - M);
          eb16[idx] = (h16)__expf(eBf[idx] - m_);
        }
        __syncthreads();
        if (tid < 144) {
          int y = tid / 6, zq = tid % 6;
          float4 acc = make_float4(0, 0, 0, 0);
          for (int s = 0; s < S; s++) {
            float a = eA[s * 24 + y];
            h4 b4 = ((const h4*)(eb16 + s * 24))[zq];
            acc.x = fmaf(a, (float)b4.x, acc.x); acc.y = fmaf(a, (float)b4.y, acc.y);
            acc.z = fmaf(a, (float)b4.z, acc.z); acc.w = fmaf(a, (float)b4.w, acc.w);
          }
          h4 t; t.x = (h16)acc.x; t.y = (h16)acc.y; t.z = (h16)acc.z; t.w = (h16)acc.w;
          ((h4*)(rrh + y * 24))[zq] = t;
        }
        __syncthreads();
        if (tid < 192) {
          int x = tid >> 3, c = tid & 7;
          const h4* e4 = (const h4*)(et16h + x * 584 + c * 72);
          const h4* r4 = (const h4*)(rrh + c * 72);
          float a0 = 0, a1 = 0;
#pragma unroll
          for (int q = 0; q < 18; q += 2) {
            h4 ev = e4[q], rv = r4[q];
            a0 = d2(ev.x, ev.y, rv.x, rv.y, a0);
            a0 = d2(ev.z, ev.w, rv.z, rv.w, a0);
            h4 e2 = e4[q + 1], r2v = r4[q + 1];
            a1 = d2(e2.x, e2.y, r2v.x, r2v.y, a1);
            a1 = d2(e2.z, e2.w, r2v.z, r2v.w, a1);
          }
          red2[tid] = a0 + a1;
        }
        __syncthreads();
        if (tid < 24) {
          float a = 0;
          for (int q = 0; q < 8; q++) a += red2[tid * 8 + q];
          gstore(bbase + (size_t)tri(i, j) * 32 + tid, M + __logf(fmaxf(a, EPSV)));
        }
      }
      // ---- drain + post own progress ----
      __builtin_amdgcn_s_waitcnt(0);
      __syncthreads();
      if (tid == 0) storeu(slotI + local, (unsigned)l);
    }
  }
  if (local == 0 && tid == 0) {
    gstore(logZg + b, gload(bbase + 496 * 32));
    __hip_atomic_fetch_add(done, 1u, __ATOMIC_RELAXED, __HIP_MEMORY_SCOPE_AGENT);
  }

  //================ outside: levels 32-local..2, neighbor-gated ================
  {
    float* ebL  = (float*)(smem + O_EA);    // 744 f (left; exp'd in place)
    float* ebRf = (float*)(smem + O_EBF);   // 744 f (right, raw)
    h16*  eb16  = (h16*)(smem + O_EB16);    // 744 h (right, exp'd fp16)
    h16*  rrh   = (h16*)(smem + O_RR);      // 576 h (w)
    float* ea24 = (float*)(smem + O_RED2);  // 24 f
    float* mLs  = (float*)(smem + O_MRL);   // 32
    float* mRs  = (float*)(smem + O_MSM);   // 32
    float* scal = (float*)(smem + O_SCAL);  // 16
    const int lastLO = 32 - local;   // first (longest-span) outside level
    for (int l = lastLO; l >= 2; l--) {
      int S = l - 1;
      // gate: left neighbor done with level l+1
      if (local > 0 && tid == 0) {
        unsigned need = (unsigned)(32 - l);
        while (loadu(slotO + local - 1) < need) __builtin_amdgcn_s_sleep(1);
      }
      __syncthreads();
      {
        int i = local, j = i + S, SN = S * 24;
        if (tid < 32) {
          float av = NEGV;
          if (tid < 24) av = la2(gload(aLb + tri(i, j) * 24 + tid), gload(aRb + tri(i, j) * 24 + tid));
          float m = av;
          for (int off = 16; off; off >>= 1) m = fmaxf(m, __shfl_xor(m, off));
          if (tid < 24) ea24[tid] = __expf(av - m);
          if (tid == 0) scal[0] = m;
        }
        __syncthreads();
        float ma = scal[0];
        if (tid < 144) {
          int y = tid / 6, zq = tid % 6;
          float4 acc = make_float4(0, 0, 0, 0);
#pragma unroll 4
          for (int x = 0; x < 24; x++) {
            float a = ea24[x];
            h4 ev = ((const h4*)(et16h + x * 584 + y * 24))[zq];
            acc.x = fmaf(a, (float)ev.x, acc.x); acc.y = fmaf(a, (float)ev.y, acc.y);
            acc.z = fmaf(a, (float)ev.z, acc.z); acc.w = fmaf(a, (float)ev.w, acc.w);
          }
          h4 t; t.x = (h16)acc.x; t.y = (h16)acc.y; t.z = (h16)acc.z; t.w = (h16)acc.w;
          ((h4*)(rrh + y * 24))[zq] = t;
        }
        for (int idx4 = tid; idx4 < 6 * S; idx4 += 256) {
          int s = idx4 / 6, q = idx4 - 6 * s;
          ((float4*)ebL)[idx4]  = ((const float4*)(bbase + (size_t)tri(i, i + s) * 32))[q];
          ((float4*)ebRf)[idx4] = ((const float4*)(bbase + (size_t)tri(i + s + 1, j) * 32))[q];
        }
        __syncthreads();
        if (tid < 8 * S) {
          int s = tid >> 3, q = tid & 7, y0 = q * 3;
          float pl = fmaxf(fmaxf(ebL[s * 24 + y0], ebL[s * 24 + y0 + 1]), ebL[s * 24 + y0 + 2]);
          float pr = fmaxf(fmaxf(ebRf[s * 24 + y0], ebRf[s * 24 + y0 + 1]), ebRf[s * 24 + y0 + 2]);
          for (int off = 4; off; off >>= 1) {
            pl = fmaxf(pl, __shfl_xor(pl, off));
            pr = fmaxf(pr, __shfl_xor(pr, off));
          }
          if (q == 0) { mLs[s] = pl; mRs[s] = pr; }
        }
        __syncthreads();
        for (int idx = tid; idx < SN; idx += 256) {
          int s = idx / 24;
          ebL[idx] = __expf(ebL[idx] - mLs[s]);
          eb16[idx] = (h16)__expf(ebRf[idx] - mRs[s]);
        }
        __syncthreads();
        for (int u = tid; u < 2 * SN; u += 256) {
          if (u < SN) {  // cL -> aL[tri(i,i+s)][y]; unique writer per level
            int s = u / 24, y = u - s * 24;
            const h4* w4 = (const h4*)(rrh + y * 24);
            const h4* r4 = (const h4*)(eb16 + s * 24);
            float acc = 0;
#pragma unroll
            for (int q = 0; q < 6; q++) {
              h4 a = w4[q], c4 = r4[q];
              acc = d2(a.x, a.y, c4.x, c4.y, acc);
              acc = d2(a.z, a.w, c4.z, c4.w, acc);
            }
            float val = __logf(fmaxf(acc, EPSV)) + ma + mRs[s];
            float* t = aLb + tri(i, i + s) * 24 + y;
            gstore(t, la2(gload(t), val));
          } else {       // cR -> aR[tri(i+s+1,j)][z]
            int u2 = u - SN;
            int s = u2 / 24, z = u2 - s * 24;
            float acc = 0;
            for (int y = 0; y < 24; y++) acc = fmaf((float)rrh[y * 24 + z], ebL[s * 24 + y], acc);
            float val = __logf(fmaxf(acc, EPSV)) + ma + mLs[s];
            float* t = aRb + tri(i + s + 1, j) * 24 + z;
            gstore(t, la2(gload(t), val));
          }
        }
      }
      // ---- drain + post own progress ----
      __builtin_amdgcn_s_waitcnt(0);
      __syncthreads();
      if (tid == 0) storeu(slotO + local, (unsigned)(33 - l));
    }
  }
  // ---- mask gate: all outside of batch b finished (slotO[0..30] == 31) ----
  if (tid < 64) {
    for (;;) {
      unsigned v = 31;
      if (tid < 31) v = loadu(slotO + tid);
      if (__ballot(v >= 31u) == ~0ull) break;
      __builtin_amdgcn_s_sleep(1);
    }
  }
  __syncthreads();

  //================ mask logits + loss ================
  {
    float* p = (float*)smem;  // 768 f, layout [n*32 + t] (overlays et16h — DP done)
    float logZv = gload(bbase + 496 * 32);
    for (int c = tid; c < 768; c += 256) {
      int n = c >> 5, t = c & 31;
      int dA = tri(t, t) * 24 + n;
      float al = gload(aLb + dA), ar = gload(aRb + dA);
      p[c] = __expf(la2(al, ar) + bbase[(size_t)tri(t, t) * 32 + n] - logZv);
    }
    __syncthreads();
    int vbase = local * 1000;
    for (int pass = 0; pass < 2; pass++) {
      int o0 = tid + pass * 512, o1 = o0 + 256;
      bool v0ok = o0 < 1000, v1ok = o1 < 1000;
      int v0 = vbase + o0, v1 = vbase + o1;
      float vr0[24], vr1[24];
#pragma unroll
      for (int n = 0; n < 24; n++) {
        vr0[n] = v0ok ? vocab[n * 32000 + v0] : 0.f;
        vr1[n] = v1ok ? vocab[n * 32000 + v1] : 0.f;
      }
      float* ob0 = out + (size_t)b * 32 * 32000 + v0;
      float* ob1 = out + (size_t)b * 32 * 32000 + v1;
      for (int t4 = 0; t4 < 32; t4 += 4) {
        float a00 = 1e-6f, a01 = 1e-6f, a02 = 1e-6f, a03 = 1e-6f;
        float a10 = 1e-6f, a11 = 1e-6f, a12 = 1e-6f, a13 = 1e-6f;
#pragma unroll 6
        for (int n = 0; n < 24; n++) {
          float4 pv = *(const float4*)(p + n * 32 + t4);
          a00 = fmaf(pv.x, vr0[n], a00); a01 = fmaf(pv.y, vr0[n], a01);
          a02 = fmaf(pv.z, vr0[n], a02); a03 = fmaf(pv.w, vr0[n], a03);
          a10 = fmaf(pv.x, vr1[n], a10); a11 = fmaf(pv.y, vr1[n], a11);
          a12 = fmaf(pv.z, vr1[n], a12); a13 = fmaf(pv.w, vr1[n], a13);
        }
        if (v0ok) {
          ob0[(size_t)(t4 + 0) * 32000] = __logf(a00);
          ob0[(size_t)(t4 + 1) * 32000] = __logf(a01);
          ob0[(size_t)(t4 + 2) * 32000] = __logf(a02);
          ob0[(size_t)(t4 + 3) * 32000] = __logf(a03);
        }
        if (v1ok) {
          ob1[(size_t)(t4 + 0) * 32000] = __logf(a10);
          ob1[(size_t)(t4 + 1) * 32000] = __logf(a11);
          ob1[(size_t)(t4 + 2) * 32000] = __logf(a12);
          ob1[(size_t)(t4 + 3) * 32000] = __logf(a13);
        }
      }
    }
    if (blk == 0 && tid == 0) {
      while (loadu(done) < 16u) __builtin_amdgcn_s_sleep(2);
      float s = 0;
      for (int q = 0; q < 16; q++) s += gload(logZg + q);
      out[16384000] = -s / 16.0f;
    }
  }
}

// ---------------------------------------------------------------- launch
extern "C" void kernel_launch(void* const* d_in, const int* in_sizes, int n_in,
                              void* d_out, int out_size, void* d_ws, size_t ws_size,
                              hipStream_t stream) {
  (void)in_sizes; (void)n_in; (void)out_size; (void)ws_size;
  const float* g_seq = (const float*)d_in[0];
  const float* Theta = (const float*)d_in[1];
  const float* vocab = (const float*)d_in[2];
  const float* lng   = (const float*)d_in[3];
  const float* lnb   = (const float*)d_in[4];
  const float* W1    = (const float*)d_in[5];
  const float* bb1   = (const float*)d_in[6];
  const float* W2    = (const float*)d_in[7];
  const float* bb2   = (const float*)d_in[8];
  float* out = (float*)d_out;

  float* ws = (float*)d_ws;
  unsigned* cnt = (unsigned*)d_ws;            // ws[0..2048) counters (memset 0)
  float* logZg  = ws + 2048;                  // 16
  float* et_g   = ws + 4096;                  // 13824
  float* beta_g = ws + 18432;                 // 16 * 16896 = 270336
  float* aL_g   = beta_g + 16 * BSTRIDE;      // 202752
  float* aR_g   = aL_g + 16 * ASTRIDE;        // 202752

  hipMemsetAsync(d_ws, 0, 8192, stream);

  void* args[] = {(void*)&g_seq, (void*)&Theta, (void*)&vocab, (void*)&lng,
                  (void*)&lnb, (void*)&W1, (void*)&bb1, (void*)&W2, (void*)&bb2,
                  (void*)&out, (void*)&et_g, (void*)&beta_g, (void*)&aL_g,
                  (void*)&aR_g, (void*)&cnt, (void*)&logZg};
  hipLaunchCooperativeKernel((const void*)mega_kernel, dim3(512), dim3(256),
                             args, 0, stream);
}

// Round 7
// 438.977 us; speedup vs baseline: 6.7213x; 1.0925x over previous
//
#include <hip/hip_runtime.h>
#include <math.h>

#define NEGV -1000000000.0f
#define EPSV 1e-38f
#define SENTU 0x7FC00001u

typedef _Float16 h16;
typedef _Float16 h2 __attribute__((ext_vector_type(2)));
typedef _Float16 h4 __attribute__((ext_vector_type(4)));

constexpr int BSTRIDE = 528 * 32;   // beta floats per batch (128B-padded cells, write-once)
constexpr int ASTRIDE = 528 * 24;   // aL/aR floats per batch

// LDS layout (bytes from smem base); total 37744 (r5-identical)
constexpr int O_WK   = 28032;  // et16h: 24 x 584 halves = 28032 B
constexpr int O_EA   = 28032;  // eA / ebL: 744 f
constexpr int O_EBF  = 31008;  // eBf / ebRf: 744 f (raw right child)
constexpr int O_EB16 = 33984;  // exp'd right child: 744 h
constexpr int O_RR   = 35472;  // rr / w: 576 h (+pad)
constexpr int O_EA24 = 36656;  // ea24: 24 f (outside)
constexpr int O_MRL  = 37424;  // 32 f (inside mrl / outside mLs)
constexpr int O_MSM  = 37552;  // 32 f (outside mRs)
constexpr int O_SCAL = 37680;  // 16 f
constexpr int SMEM_SZ = 37744;

__device__ __forceinline__ int tri(int i, int j) { return ((j * (j + 1)) >> 1) + i; }
__device__ __forceinline__ float la2(float a, float c) {
  float mx = fmaxf(a, c), mn = fminf(a, c);
  return mx + log1pf(__expf(mn - mx));
}
// relaxed agent-scope ops — bypass caches, hit the coherent point (r0/r2/r5-proven)
__device__ __forceinline__ void gstore(float* p, float v) {
  __hip_atomic_store(p, v, __ATOMIC_RELAXED, __HIP_MEMORY_SCOPE_AGENT);
}
__device__ __forceinline__ float gload(const float* p) {
  return __hip_atomic_load(p, __ATOMIC_RELAXED, __HIP_MEMORY_SCOPE_AGENT);
}
__device__ __forceinline__ void storeu(unsigned* p, unsigned v) {
  __hip_atomic_store(p, v, __ATOMIC_RELAXED, __HIP_MEMORY_SCOPE_AGENT);
}
__device__ __forceinline__ unsigned loadu(const unsigned* p) {
  return __hip_atomic_load(p, __ATOMIC_RELAXED, __HIP_MEMORY_SCOPE_AGENT);
}
__device__ __forceinline__ float d2(h16 ax, h16 ay, h16 bx, h16 by, float c) {
#if __has_builtin(__builtin_amdgcn_fdot2)
  h2 a; a.x = ax; a.y = ay;
  h2 b; b.x = bx; b.y = by;
  return __builtin_amdgcn_fdot2(a, b, c, false);
#else
  return c + (float)ax * (float)bx + (float)ay * (float)by;
#endif
}
__device__ __forceinline__ float wmax64(float v) {
#pragma unroll
  for (int off = 32; off; off >>= 1) v = fmaxf(v, __shfl_xor(v, off));
  return v;
}

#define MAX12(A, B, C)                                                        \
  fmaxf(fmaxf(fmaxf(fmaxf(A.x, A.y), fmaxf(A.z, A.w)),                        \
              fmaxf(fmaxf(B.x, B.y), fmaxf(B.z, B.w))),                       \
        fmaxf(fmaxf(C.x, C.y), fmaxf(C.z, C.w)))

// 512 blocks x 256 threads, cooperative. b = blk&15, local = blk>>4.
// Inside sync: DATA-POLLING on sentinel-initialized beta cells (no flags).
// Outside sync: r2/r5-proven left-neighbor slotO chain, post split cR|cL.
__global__ void __launch_bounds__(256, 2) mega_kernel(
    const float* __restrict__ g_seq, const float* __restrict__ Theta,
    const float* __restrict__ vocab, const float* __restrict__ lng,
    const float* __restrict__ lnb, const float* __restrict__ W1,
    const float* __restrict__ bb1, const float* __restrict__ W2,
    const float* __restrict__ bb2, float* __restrict__ out,
    float* __restrict__ et_g, float* __restrict__ beta_g,
    float* __restrict__ aL_g, float* __restrict__ aR_g,
    unsigned* __restrict__ cnt, float* __restrict__ logZg) {
  __shared__ __align__(16) unsigned char smem[SMEM_SZ];
  h16* et16h = (h16*)smem;              // 24 x 584 halves
  float* wk = (float*)(smem + O_WK);    // frontend scratch (1192 f)
  const int tid = threadIdx.x;
  const int blk = blockIdx.x;
  const int b = blk & 15, local = blk >> 4;
  unsigned* gcnt  = cnt;                    // init stage-2 (16 arrivals)
  unsigned* done  = cnt + 8;                // logZ done count
  unsigned* ibc   = cnt + 16 + b * 16;      // init stage-1 per batch
  unsigned* slotO = cnt + 512 + b * 64 + 32;  // 32 outside progress words
  float* bbase = beta_g + b * BSTRIDE;
  float* aLb = aL_g + b * ASTRIDE;
  float* aRb = aR_g + b * ASTRIDE;

  //================ phase 0: frontend (task bt = blk) ================
  {
    float* g = wk;                       // 512
    float2* red = (float2*)(wk + 512);   // 512
    float* hb = wk + 1024;               // 128
    float* ob = wk + 1152;               // 32
    float* sc = wk + 1184;               // 8
    float2 raw = ((const float2*)(g_seq + (size_t)blk * 512))[tid];
    red[tid] = make_float2(raw.x + raw.y, raw.x * raw.x + raw.y * raw.y);
    __syncthreads();
    if (tid < 128) { float2 o = red[tid + 128], m = red[tid]; red[tid] = make_float2(m.x + o.x, m.y + o.y); }
    __syncthreads();
    if (tid < 64) {
      float2 v = red[tid], o = red[tid + 64];
      v.x += o.x; v.y += o.y;
      for (int off = 32; off; off >>= 1) { v.x += __shfl_xor(v.x, off); v.y += __shfl_xor(v.y, off); }
      if (tid == 0) {
        float mu = v.x / 512.0f;
        float var = v.y / 512.0f - mu * mu;
        sc[0] = mu; sc[1] = rsqrtf(var + 1e-5f);
      }
    }
    __syncthreads();
    float mu = sc[0], rstd = sc[1];
    g[2 * tid]     = (raw.x - mu) * rstd * lng[2 * tid]     + lnb[2 * tid];
    g[2 * tid + 1] = (raw.y - mu) * rstd * lng[2 * tid + 1] + lnb[2 * tid + 1];
    __syncthreads();
    {
      int j = tid & 127, hh = tid >> 7, c0 = hh * 256;
      float a0 = 0, a1 = 0, a2 = 0, a3 = 0;
      for (int c = 0; c < 256; c += 4) {
        a0 = fmaf(g[c0 + c],     W1[(c0 + c) * 128 + j],     a0);
        a1 = fmaf(g[c0 + c + 1], W1[(c0 + c + 1) * 128 + j], a1);
        a2 = fmaf(g[c0 + c + 2], W1[(c0 + c + 2) * 128 + j], a2);
        a3 = fmaf(g[c0 + c + 3], W1[(c0 + c + 3) * 128 + j], a3);
      }
      ((float*)red)[tid] = (a0 + a1) + (a2 + a3);
    }
    __syncthreads();
    if (tid < 128) {
      float a = ((float*)red)[tid] + ((float*)red)[tid + 128] + bb1[tid];
      hb[tid] = 0.5f * a * (1.0f + erff(a * 0.70710678118654752f));
    }
    __syncthreads();
    if (tid < 192) {
      int n = tid >> 3, q = tid & 7;
      float a = 0;
      for (int k = 0; k < 16; k++) a = fmaf(hb[q * 16 + k], W2[(q * 16 + k) * 24 + n], a);
      ((float*)red)[tid] = a;
    }
    __syncthreads();
    if (tid < 24) {
      float a = bb2[tid];
      for (int q = 0; q < 8; q++) a += ((float*)red)[tid * 8 + q];
      ob[tid] = a;
    }
    __syncthreads();
    if (tid == 0) {
      float m = ob[0];
      for (int n = 1; n < 24; n++) m = fmaxf(m, ob[n]);
      float s = 0;
      for (int n = 0; n < 24; n++) s += __expf(ob[n] - m);
      sc[2] = m + __logf(s);
    }
    __syncthreads();
    if (tid < 24) {
      int fb = blk >> 5, ft = blk & 31;
      gstore(beta_g + (size_t)fb * BSTRIDE + tri(ft, ft) * 32 + tid, ob[tid] - sc[2]);
    }
  }
  // theta rows (tm dropped — exact; et = exp(theta_log) <= 1)
  if (tid < 64) {
    int z = tid & 31;
    bool up = tid >= 32;
    int row = up ? (512 + blk) : blk;
    bool valid = (!up) || (blk < 64);
    float v = (z < 24 && valid) ? Theta[row * 24 + z] : NEGV;
    float m = v;
    for (int off = 16; off; off >>= 1) m = fmaxf(m, __shfl_xor(m, off));
    float e = (z < 24 && valid) ? __expf(v - m) : 0.f;
    float s = e;
    for (int off = 16; off; off >>= 1) s += __shfl_xor(s, off);
    float lse = m + __logf(s);
    if (z < 24 && valid) gstore(et_g + row * 24 + z, __expf(v - lse));
  }
  // alpha init (aL||aR contiguous); root aL[b][tri(0,31)][0] = 0 folded in
  for (int idx = blk * 256 + tid; idx < 2 * 16 * ASTRIDE; idx += 131072) {
    float v = NEGV;
    if (idx < 16 * ASTRIDE && (idx % ASTRIDE) == 11904) v = 0.f;
    gstore(aL_g + idx, v);
  }
  // beta sentinel init: words 0..23 of every NON-diagonal cell (diag cells are
  // written by the frontend concurrently — disjoint addresses)
  for (int idx = blk * 256 + tid; idx < 16 * BSTRIDE; idx += 131072) {
    int w = idx % BSTRIDE;
    int cell = w >> 5, wic = w & 31;
    if (wic >= 24) continue;
    int t0 = (int)((sqrtf(8.f * (float)cell + 9.f) - 3.f) * 0.5f + 0.5f);
    bool isDiag = false;
#pragma unroll
    for (int dt = -1; dt <= 1; ++dt) {
      int t = t0 + dt;
      if (t >= 0 && ((t * (t + 3)) >> 1) == cell) isDiag = true;
    }
    if (!isDiag) gstore(beta_g + idx, __uint_as_float(SENTU));
  }
  // ---- init global barrier (two-stage, r2-proven) ----
  __builtin_amdgcn_s_waitcnt(0);
  __syncthreads();
  if (tid == 0) {
    __hip_atomic_fetch_add(ibc, 1u, __ATOMIC_RELAXED, __HIP_MEMORY_SCOPE_AGENT);
    if (local == 0) {
      while (loadu(ibc) < 32u) __builtin_amdgcn_s_sleep(2);
      __hip_atomic_fetch_add(gcnt, 1u, __ATOMIC_RELAXED, __HIP_MEMORY_SCOPE_AGENT);
    }
    while (loadu(gcnt) < 16u) __builtin_amdgcn_s_sleep(2);
  }
  __syncthreads();

  // stage et into LDS as fp16, row stride 584 halves (write-once region)
  for (int i4 = tid; i4 < 3456; i4 += 256) {
    int f = i4 * 4;
    int x = f / 576, r = f - x * 576;
    float4 v = ((const float4*)et_g)[i4];
    h4 t; t.x = (h16)v.x; t.y = (h16)v.y; t.z = (h16)v.z; t.w = (h16)v.w;
    *(h4*)(et16h + x * 584 + r) = t;
  }
  __syncthreads();

  //================ inside: levels 2..32-local, DATA-POLLED ================
  {
    float* eA   = (float*)(smem + O_EA);    // 744 f (left; exp'd in place)
    float* eBf  = (float*)(smem + O_EBF);   // 744 f (right, raw)
    h16*  eb16  = (h16*)(smem + O_EB16);    // 744 h (right, exp'd fp16)
    h16*  rrh   = (h16*)(smem + O_RR);      // 576 h
    float* mrl  = (float*)(smem + O_MRL);   // 32
    float* scal = (float*)(smem + O_SCAL);  // 16
    const int lastLI = 32 - local;   // local=31 -> loop skipped
    for (int l = 2; l <= lastLI; l++) {
      int S = l - 1;
      int i = local, j = i + S, SN = S * 24;
      // A: staging. Own row: plain float4. Right column: per-word polls on the
      // sentinel (issue-all-then-repair; writers progress independently).
      for (int idx4 = tid; idx4 < 6 * S; idx4 += 256) {
        int s = idx4 / 6, q = idx4 - 6 * s;
        ((float4*)eA)[idx4] = ((const float4*)(bbase + (size_t)tri(i, i + s) * 32))[q];
        const float* cp = bbase + (size_t)tri(i + s + 1, j) * 32 + q * 4;
        float w0 = gload(cp), w1 = gload(cp + 1), w2 = gload(cp + 2), w3 = gload(cp + 3);
        while ((__float_as_uint(w0) == SENTU) | (__float_as_uint(w1) == SENTU) |
               (__float_as_uint(w2) == SENTU) | (__float_as_uint(w3) == SENTU)) {
          __builtin_amdgcn_s_sleep(1);
          w0 = gload(cp); w1 = gload(cp + 1); w2 = gload(cp + 2); w3 = gload(cp + 3);
        }
        float4 t4; t4.x = w0; t4.y = w1; t4.z = w2; t4.w = w3;
        ((float4*)eBf)[idx4] = t4;
      }
      __syncthreads();
      // B: per-s maxes + global M, wave 0 only (2 lanes per s)
      if (tid < 64) {
        int s = tid >> 1, h12 = tid & 1;
        float pa = NEGV, pb = NEGV;
        if (s < S) {
          const float4* ra = (const float4*)(eA + s * 24 + h12 * 12);
          float4 A = ra[0], B = ra[1], C = ra[2];
          pa = MAX12(A, B, C);
          const float4* rb = (const float4*)(eBf + s * 24 + h12 * 12);
          float4 D = rb[0], E = rb[1], F = rb[2];
          pb = MAX12(D, E, F);
        }
        pa = fmaxf(pa, __shfl_xor(pa, 1));
        pb = fmaxf(pb, __shfl_xor(pb, 1));
        if (s < S && h12 == 0) mrl[s] = pb;
        float M0 = wmax64((s < S) ? pa + pb : NEGV);
        if (tid == 0) scal[0] = M0;
      }
      __syncthreads();
      // C: exp
      float M = scal[0];
      for (int idx = tid; idx < SN; idx += 256) {
        int s = idx / 24;
        float m_ = mrl[s];
        eA[idx] = __expf(eA[idx] + m_ - M);
        eb16[idx] = (h16)__expf(eBf[idx] - m_);
      }
      __syncthreads();
      // D: rank-1 rr[y][z] = sum_s eA[s][y]*eb16[s][z]
      if (tid < 144) {
        int y = tid / 6, zq = tid % 6;
        float4 acc = make_float4(0, 0, 0, 0);
        for (int s = 0; s < S; s++) {
          float a = eA[s * 24 + y];
          h4 b4 = ((const h4*)(eb16 + s * 24))[zq];
          acc.x = fmaf(a, (float)b4.x, acc.x); acc.y = fmaf(a, (float)b4.y, acc.y);
          acc.z = fmaf(a, (float)b4.z, acc.z); acc.w = fmaf(a, (float)b4.w, acc.w);
        }
        h4 t; t.x = (h16)acc.x; t.y = (h16)acc.y; t.z = (h16)acc.z; t.w = (h16)acc.w;
        ((h4*)(rrh + y * 24))[zq] = t;
      }
      __syncthreads();
      // E: matvec + write, wave 0 (2 lanes per x)
      if (tid < 48) {
        int x = tid >> 1, hh = tid & 1;
        const h4* ep = (const h4*)(et16h + x * 584 + hh * 288);
        const h4* rp = (const h4*)(rrh + hh * 288);
        float a2 = 0.f;
#pragma unroll 8
        for (int q = 0; q < 72; ++q) {
          h4 ev = ep[q], rv = rp[q];
          a2 = d2(ev.x, ev.y, rv.x, rv.y, a2);
          a2 = d2(ev.z, ev.w, rv.z, rv.w, a2);
        }
        a2 += __shfl_xor(a2, 1);
        if (hh == 0)
          gstore(bbase + (size_t)tri(i, j) * 32 + x, M + __logf(fmaxf(a2, EPSV)));
      }
      // drain (own-row reuse next level; neighbor sees data via LLC directly)
      __builtin_amdgcn_s_waitcnt(0);
      __syncthreads();
    }
  }
  if (local == 0 && tid == 0) {
    gstore(logZg + b, gload(bbase + 496 * 32));
    __builtin_amdgcn_s_waitcnt(0);
    __hip_atomic_fetch_add(done, 1u, __ATOMIC_RELAXED, __HIP_MEMORY_SCOPE_AGENT);
  }

  //================ outside: levels 32-local..2, neighbor-gated ================
  {
    float* ebL  = (float*)(smem + O_EA);    // 744 f (left; exp'd in place)
    float* ebRf = (float*)(smem + O_EBF);   // 744 f (right, raw)
    h16*  eb16  = (h16*)(smem + O_EB16);    // 744 h (right, exp'd fp16)
    h16*  rrh   = (h16*)(smem + O_RR);      // 576 h (w)
    float* ea24 = (float*)(smem + O_EA24);  // 24 f
    float* mLs  = (float*)(smem + O_MRL);   // 32
    float* mRs  = (float*)(smem + O_MSM);   // 32
    float* scal = (float*)(smem + O_SCAL);  // 16
    const int lastLO = 32 - local;
    for (int l = lastLO; l >= 2; l--) {
      int S = l - 1;
      int i = local, j = i + S, SN = S * 24;
      // gate: left neighbor's cR of level l+1 done
      if (local > 0 && tid == 0) {
        unsigned need = (unsigned)(32 - l);
        while (loadu(slotO + local - 1) < need) __builtin_amdgcn_s_sleep(1);
      }
      __builtin_amdgcn_s_waitcnt(0);   // drain prev iteration's cL (per-wave)
      __syncthreads();
      // A: wave0 = alpha read+prep; waves1-3 = beta staging (final cells)
      if (tid < 64) {
        float av = NEGV;
        if (tid < 24)
          av = la2(gload(aLb + tri(i, j) * 24 + tid), gload(aRb + tri(i, j) * 24 + tid));
        float mav = wmax64(av);
        if (tid < 24) ea24[tid] = __expf(av - mav);
        if (tid == 0) scal[0] = mav;
      } else {
        for (int idx4 = tid - 64; idx4 < 6 * S; idx4 += 192) {
          int s = idx4 / 6, q = idx4 - 6 * s;
          ((float4*)ebL)[idx4]  = ((const float4*)(bbase + (size_t)tri(i, i + s) * 32))[q];
          ((float4*)ebRf)[idx4] = ((const float4*)(bbase + (size_t)tri(i + s + 1, j) * 32))[q];
        }
      }
      __syncthreads();
      float ma = scal[0];
      // B: wave0 = per-s maxes; waves1-3 (tid 64..207) = w-compute
      if (tid < 64) {
        int s = tid >> 1, h12 = tid & 1;
        float pl = NEGV, pr = NEGV;
        if (s < S) {
          const float4* ra = (const float4*)(ebL + s * 24 + h12 * 12);
          float4 A = ra[0], B = ra[1], C = ra[2];
          pl = MAX12(A, B, C);
          const float4* rb = (const float4*)(ebRf + s * 24 + h12 * 12);
          float4 D = rb[0], E = rb[1], F = rb[2];
          pr = MAX12(D, E, F);
        }
        pl = fmaxf(pl, __shfl_xor(pl, 1));
        pr = fmaxf(pr, __shfl_xor(pr, 1));
        if (s < S && h12 == 0) { mLs[s] = pl; mRs[s] = pr; }
      } else if (tid < 208) {
        int t = tid - 64, y = t / 6, zq = t % 6;
        float4 acc = make_float4(0, 0, 0, 0);
#pragma unroll 4
        for (int x = 0; x < 24; x++) {
          float a = ea24[x];
          h4 ev = ((const h4*)(et16h + x * 584 + y * 24))[zq];
          acc.x = fmaf(a, (float)ev.x, acc.x); acc.y = fmaf(a, (float)ev.y, acc.y);
          acc.z = fmaf(a, (float)ev.z, acc.z); acc.w = fmaf(a, (float)ev.w, acc.w);
        }
        h4 t4; t4.x = (h16)acc.x; t4.y = (h16)acc.y; t4.z = (h16)acc.z; t4.w = (h16)acc.w;
        ((h4*)(rrh + y * 24))[zq] = t4;
      }
      __syncthreads();
      // C: exp
      for (int idx = tid; idx < SN; idx += 256) {
        int s = idx / 24;
        ebL[idx] = __expf(ebL[idx] - mLs[s]);
        eb16[idx] = (h16)__expf(ebRf[idx] - mRs[s]);
      }
      __syncthreads();
      // D: cR -> aR[tri(i+s+1,j)][z] (chain-exclusive RMW)
      for (int u = tid; u < SN; u += 256) {
        int s = u / 24, z = u - s * 24;
        float acc = 0;
        for (int y = 0; y < 24; y++) acc = fmaf((float)rrh[y * 24 + z], ebL[s * 24 + y], acc);
        float val = __logf(fmaxf(acc, EPSV)) + ma + mLs[s];
        float* t = aRb + tri(i + s + 1, j) * 24 + z;
        gstore(t, la2(gload(t), val));
      }
      __builtin_amdgcn_s_waitcnt(0);
      __syncthreads();
      if (tid == 0) storeu(slotO + local, (unsigned)(33 - l));
      // E: cL -> aL[tri(i,i+s)][y] (own-row; drained at next iteration entry)
      for (int u = tid; u < SN; u += 256) {
        int s = u / 24, y = u - s * 24;
        const h4* w4 = (const h4*)(rrh + y * 24);
        const h4* r4 = (const h4*)(eb16 + s * 24);
        float acc = 0;
#pragma unroll
        for (int q = 0; q < 6; q++) {
          h4 a = w4[q], c4 = r4[q];
          acc = d2(a.x, a.y, c4.x, c4.y, acc);
          acc = d2(a.z, a.w, c4.z, c4.w, acc);
        }
        float val = __logf(fmaxf(acc, EPSV)) + ma + mRs[s];
        float* t = aLb + tri(i, i + s) * 24 + y;
        gstore(t, la2(gload(t), val));
      }
    }
    // final drain + completion post (protects mask's aL-diag reads)
    __builtin_amdgcn_s_waitcnt(0);
    __syncthreads();
    if (tid == 0) storeu(slotO + local, 32u);
  }

  //================ mask logits + loss ================
  {
    int vbase = local * 1000;
    // prefetch pass-0 vocab (inputs — no gate needed)
    float pv0[24], pv1[24];
    {
      int o0 = tid, o1 = tid + 256;
      bool k0 = o0 < 1000, k1 = o1 < 1000;
#pragma unroll
      for (int n = 0; n < 24; n++) {
        pv0[n] = k0 ? vocab[n * 32000 + vbase + o0] : 0.f;
        pv1[n] = k1 ? vocab[n * 32000 + vbase + o1] : 0.f;
      }
    }
    // gate: all outside of batch b fully finished (slotO[0..30] == 32)
    if (tid < 64) {
      for (;;) {
        unsigned v = 32;
        if (tid < 31) v = loadu(slotO + tid);
        if (__ballot(v >= 32u) == ~0ull) break;
        __builtin_amdgcn_s_sleep(1);
      }
    }
    __syncthreads();
    float* p = (float*)smem;  // 768 f, layout [n*32 + t] (overlays et16h — DP done)
    float logZv = gload(bbase + 496 * 32);
    for (int c = tid; c < 768; c += 256) {
      int n = c >> 5, t = c & 31;
      int dA = tri(t, t) * 24 + n;
      float al = gload(aLb + dA), ar = gload(aRb + dA);
      p[c] = __expf(la2(al, ar) + bbase[(size_t)tri(t, t) * 32 + n] - logZv);
    }
    __syncthreads();
    for (int pass = 0; pass < 2; pass++) {
      int o0 = tid + pass * 512, o1 = o0 + 256;
      bool v0ok = o0 < 1000, v1ok = o1 < 1000;
      int v0 = vbase + o0, v1 = vbase + o1;
      if (pass == 1) {
#pragma unroll
        for (int n = 0; n < 24; n++) {
          pv0[n] = v0ok ? vocab[n * 32000 + v0] : 0.f;
          pv1[n] = v1ok ? vocab[n * 32000 + v1] : 0.f;
        }
      }
      float* ob0 = out + (size_t)b * 32 * 32000 + v0;
      float* ob1 = out + (size_t)b * 32 * 32000 + v1;
      for (int t4 = 0; t4 < 32; t4 += 4) {
        float a00 = 1e-6f, a01 = 1e-6f, a02 = 1e-6f, a03 = 1e-6f;
        float a10 = 1e-6f, a11 = 1e-6f, a12 = 1e-6f, a13 = 1e-6f;
#pragma unroll 6
        for (int n = 0; n < 24; n++) {
          float4 pv = *(const float4*)(p + n * 32 + t4);
          a00 = fmaf(pv.x, pv0[n], a00); a01 = fmaf(pv.y, pv0[n], a01);
          a02 = fmaf(pv.z, pv0[n], a02); a03 = fmaf(pv.w, pv0[n], a03);
          a10 = fmaf(pv.x, pv1[n], a10); a11 = fmaf(pv.y, pv1[n], a11);
          a12 = fmaf(pv.z, pv1[n], a12); a13 = fmaf(pv.w, pv1[n], a13);
        }
        if (v0ok) {
          ob0[(size_t)(t4 + 0) * 32000] = __logf(a00);
          ob0[(size_t)(t4 + 1) * 32000] = __logf(a01);
          ob0[(size_t)(t4 + 2) * 32000] = __logf(a02);
          ob0[(size_t)(t4 + 3) * 32000] = __logf(a03);
        }
        if (v1ok) {
          ob1[(size_t)(t4 + 0) * 32000] = __logf(a10);
          ob1[(size_t)(t4 + 1) * 32000] = __logf(a11);
          ob1[(size_t)(t4 + 2) * 32000] = __logf(a12);
          ob1[(size_t)(t4 + 3) * 32000] = __logf(a13);
        }
      }
    }
    if (blk == 0 && tid == 0) {
      while (loadu(done) < 16u) __builtin_amdgcn_s_sleep(2);
      float s = 0;
      for (int q = 0; q < 16; q++) s += gload(logZg + q);
      out[16384000] = -s / 16.0f;
    }
  }
}

// ---------------------------------------------------------------- launch
extern "C" void kernel_launch(void* const* d_in, const int* in_sizes, int n_in,
                              void* d_out, int out_size, void* d_ws, size_t ws_size,
                              hipStream_t stream) {
  (void)in_sizes; (void)n_in; (void)out_size; (void)ws_size;
  const float* g_seq = (const float*)d_in[0];
  const float* Theta = (const float*)d_in[1];
  const float* vocab = (const float*)d_in[2];
  const float* lng   = (const float*)d_in[3];
  const float* lnb   = (const float*)d_in[4];
  const float* W1    = (const float*)d_in[5];
  const float* bb1   = (const float*)d_in[6];
  const float* W2    = (const float*)d_in[7];
  const float* bb2   = (const float*)d_in[8];
  float* out = (float*)d_out;

  float* ws = (float*)d_ws;
  unsigned* cnt = (unsigned*)d_ws;            // ws[0..2048) counters (memset 0)
  float* logZg  = ws + 2048;                  // 16
  float* et_g   = ws + 4096;                  // 13824
  float* beta_g = ws + 18432;                 // 16 * 16896 = 270336
  float* aL_g   = beta_g + 16 * BSTRIDE;      // 202752
  float* aR_g   = aL_g + 16 * ASTRIDE;        // 202752

  hipMemsetAsync(d_ws, 0, 8192, stream);

  void* args[] = {(void*)&g_seq, (void*)&Theta, (void*)&vocab, (void*)&lng,
                  (void*)&lnb, (void*)&W1, (void*)&bb1, (void*)&W2, (void*)&bb2,
                  (void*)&out, (void*)&et_g, (void*)&beta_g, (void*)&aL_g,
                  (void*)&aR_g, (void*)&cnt, (void*)&logZg};
  hipLaunchCooperativeKernel((const void*)mega_kernel, dim3(512), dim3(256),
                             args, 0, stream);
}

// Round 8
// 421.592 us; speedup vs baseline: 6.9984x; 1.0412x over previous
//
#include <hip/hip_runtime.h>
#include <math.h>

#define NEGV -1000000000.0f
#define EPSV 1e-38f
#define SENTU 0x7FC00001u

typedef _Float16 h16;
typedef _Float16 h2 __attribute__((ext_vector_type(2)));
typedef _Float16 h4 __attribute__((ext_vector_type(4)));

constexpr int BSTRIDE = 528 * 32;   // beta floats per batch (128B-padded cells, write-once)
constexpr int ASTRIDE = 528 * 24;   // aL(diag-only)/aR floats per batch

// LDS layout (bytes from smem base); total 45616
constexpr int O_WK    = 28032;  // frontend scratch 1192 f (overlays betaOwn/aLOwn; frontend-only)
constexpr int O_BOWN  = 28032;  // betaOwn: 32 x 24 f (own beta row)
constexpr int O_ALOWN = 31104;  // aLOwn: 32 x 24 f (own aL row)
constexpr int O_EA    = 34176;  // eA / ebL: 744 f
constexpr int O_EBF   = 37152;  // eBf / ebRf: 744 f (raw right child)
constexpr int O_EB16  = 40128;  // exp'd right child: 744 h
constexpr int O_RR    = 41616;  // rr / w: 576 h (+pad)
constexpr int O_WT    = 42800;  // wT: 24 x 25 f (outside, [z][y] f32 mirror)
constexpr int O_EA24  = 45200;  // ea24: 24 f
constexpr int O_MRL   = 45296;  // 32 f (inside mrl / outside mLs)
constexpr int O_MSM   = 45424;  // 32 f (outside mRs)
constexpr int O_SCAL  = 45552;  // 16 f
constexpr int SMEM_SZ = 45616;

__device__ __forceinline__ int tri(int i, int j) { return ((j * (j + 1)) >> 1) + i; }
__device__ __forceinline__ float la2(float a, float c) {
  float mx = fmaxf(a, c), mn = fminf(a, c);
  return mx + log1pf(__expf(mn - mx));
}
// relaxed agent-scope ops — bypass caches, hit the coherent point (r0/r2/r5/r7-proven)
__device__ __forceinline__ void gstore(float* p, float v) {
  __hip_atomic_store(p, v, __ATOMIC_RELAXED, __HIP_MEMORY_SCOPE_AGENT);
}
__device__ __forceinline__ float gload(const float* p) {
  return __hip_atomic_load(p, __ATOMIC_RELAXED, __HIP_MEMORY_SCOPE_AGENT);
}
__device__ __forceinline__ void storeu(unsigned* p, unsigned v) {
  __hip_atomic_store(p, v, __ATOMIC_RELAXED, __HIP_MEMORY_SCOPE_AGENT);
}
__device__ __forceinline__ unsigned loadu(const unsigned* p) {
  return __hip_atomic_load(p, __ATOMIC_RELAXED, __HIP_MEMORY_SCOPE_AGENT);
}
__device__ __forceinline__ float d2(h16 ax, h16 ay, h16 bx, h16 by, float c) {
#if __has_builtin(__builtin_amdgcn_fdot2)
  h2 a; a.x = ax; a.y = ay;
  h2 b; b.x = bx; b.y = by;
  return __builtin_amdgcn_fdot2(a, b, c, false);
#else
  return c + (float)ax * (float)bx + (float)ay * (float)by;
#endif
}
__device__ __forceinline__ float wmax64(float v) {
#pragma unroll
  for (int off = 32; off; off >>= 1) v = fmaxf(v, __shfl_xor(v, off));
  return v;
}

#define MAX12(A, B, C)                                                        \
  fmaxf(fmaxf(fmaxf(fmaxf(A.x, A.y), fmaxf(A.z, A.w)),                        \
              fmaxf(fmaxf(B.x, B.y), fmaxf(B.z, B.w))),                       \
        fmaxf(fmaxf(C.x, C.y), fmaxf(C.z, C.w)))

// 512 blocks x 256 threads, cooperative. b = blk&15, local = blk>>4.
// Inside sync: DATA-POLLING on sentinel-initialized beta cells (r7-proven).
// Outside sync: left-neighbor slotO chain, post after cR (r7-proven).
// NEW: own beta row + own aL row live in LDS (block-private by construction).
__global__ void __launch_bounds__(256, 2) mega_kernel(
    const float* __restrict__ g_seq, const float* __restrict__ Theta,
    const float* __restrict__ vocab, const float* __restrict__ lng,
    const float* __restrict__ lnb, const float* __restrict__ W1,
    const float* __restrict__ bb1, const float* __restrict__ W2,
    const float* __restrict__ bb2, float* __restrict__ out,
    float* __restrict__ et_g, float* __restrict__ beta_g,
    float* __restrict__ aL_g, float* __restrict__ aR_g,
    unsigned* __restrict__ cnt, float* __restrict__ logZg) {
  __shared__ __align__(16) unsigned char smem[SMEM_SZ];
  h16* et16h = (h16*)smem;              // 24 x 584 halves
  float* wk = (float*)(smem + O_WK);    // frontend scratch (1192 f)
  float* betaOwn = (float*)(smem + O_BOWN);  // [s][24]
  float* aLOwn   = (float*)(smem + O_ALOWN); // [s][24] (cell (i, i+s))
  const int tid = threadIdx.x;
  const int blk = blockIdx.x;
  const int b = blk & 15, local = blk >> 4;
  unsigned* gcnt  = cnt;                    // init stage-2 (16 arrivals)
  unsigned* done  = cnt + 8;                // logZ done count
  unsigned* ibc   = cnt + 16 + b * 16;      // init stage-1 per batch
  unsigned* slotO = cnt + 512 + b * 64 + 32;  // 32 outside progress words
  float* bbase = beta_g + b * BSTRIDE;
  float* aLb = aL_g + b * ASTRIDE;
  float* aRb = aR_g + b * ASTRIDE;

  //================ phase 0: frontend (task bt = blk) ================
  {
    float* g = wk;                       // 512
    float2* red = (float2*)(wk + 512);   // 512
    float* hb = wk + 1024;               // 128
    float* ob = wk + 1152;               // 32
    float* sc = wk + 1184;               // 8
    float2 raw = ((const float2*)(g_seq + (size_t)blk * 512))[tid];
    red[tid] = make_float2(raw.x + raw.y, raw.x * raw.x + raw.y * raw.y);
    __syncthreads();
    if (tid < 128) { float2 o = red[tid + 128], m = red[tid]; red[tid] = make_float2(m.x + o.x, m.y + o.y); }
    __syncthreads();
    if (tid < 64) {
      float2 v = red[tid], o = red[tid + 64];
      v.x += o.x; v.y += o.y;
      for (int off = 32; off; off >>= 1) { v.x += __shfl_xor(v.x, off); v.y += __shfl_xor(v.y, off); }
      if (tid == 0) {
        float mu = v.x / 512.0f;
        float var = v.y / 512.0f - mu * mu;
        sc[0] = mu; sc[1] = rsqrtf(var + 1e-5f);
      }
    }
    __syncthreads();
    float mu = sc[0], rstd = sc[1];
    g[2 * tid]     = (raw.x - mu) * rstd * lng[2 * tid]     + lnb[2 * tid];
    g[2 * tid + 1] = (raw.y - mu) * rstd * lng[2 * tid + 1] + lnb[2 * tid + 1];
    __syncthreads();
    {
      int j = tid & 127, hh = tid >> 7, c0 = hh * 256;
      float a0 = 0, a1 = 0, a2 = 0, a3 = 0;
      for (int c = 0; c < 256; c += 4) {
        a0 = fmaf(g[c0 + c],     W1[(c0 + c) * 128 + j],     a0);
        a1 = fmaf(g[c0 + c + 1], W1[(c0 + c + 1) * 128 + j], a1);
        a2 = fmaf(g[c0 + c + 2], W1[(c0 + c + 2) * 128 + j], a2);
        a3 = fmaf(g[c0 + c + 3], W1[(c0 + c + 3) * 128 + j], a3);
      }
      ((float*)red)[tid] = (a0 + a1) + (a2 + a3);
    }
    __syncthreads();
    if (tid < 128) {
      float a = ((float*)red)[tid] + ((float*)red)[tid + 128] + bb1[tid];
      hb[tid] = 0.5f * a * (1.0f + erff(a * 0.70710678118654752f));
    }
    __syncthreads();
    if (tid < 192) {
      int n = tid >> 3, q = tid & 7;
      float a = 0;
      for (int k = 0; k < 16; k++) a = fmaf(hb[q * 16 + k], W2[(q * 16 + k) * 24 + n], a);
      ((float*)red)[tid] = a;
    }
    __syncthreads();
    if (tid < 24) {
      float a = bb2[tid];
      for (int q = 0; q < 8; q++) a += ((float*)red)[tid * 8 + q];
      ob[tid] = a;
    }
    __syncthreads();
    if (tid == 0) {
      float m = ob[0];
      for (int n = 1; n < 24; n++) m = fmaxf(m, ob[n]);
      float s = 0;
      for (int n = 0; n < 24; n++) s += __expf(ob[n] - m);
      sc[2] = m + __logf(s);
    }
    __syncthreads();
    if (tid < 24) {
      int fb = blk >> 5, ft = blk & 31;
      gstore(beta_g + (size_t)fb * BSTRIDE + tri(ft, ft) * 32 + tid, ob[tid] - sc[2]);
    }
  }
  // theta rows (tm dropped — exact; et = exp(theta_log) <= 1)
  if (tid < 64) {
    int z = tid & 31;
    bool up = tid >= 32;
    int row = up ? (512 + blk) : blk;
    bool valid = (!up) || (blk < 64);
    float v = (z < 24 && valid) ? Theta[row * 24 + z] : NEGV;
    float m = v;
    for (int off = 16; off; off >>= 1) m = fmaxf(m, __shfl_xor(m, off));
    float e = (z < 24 && valid) ? __expf(v - m) : 0.f;
    float s = e;
    for (int off = 16; off; off >>= 1) s += __shfl_xor(s, off);
    float lse = m + __logf(s);
    if (z < 24 && valid) gstore(et_g + row * 24 + z, __expf(v - lse));
  }
  // aR init (all NEGV); aL is LDS-resident now (only diags published at end)
  for (int idx = blk * 256 + tid; idx < 16 * ASTRIDE; idx += 131072)
    gstore(aR_g + idx, NEGV);
  // beta sentinel init: words 0..23 of every NON-diagonal cell
  for (int idx = blk * 256 + tid; idx < 16 * BSTRIDE; idx += 131072) {
    int w = idx % BSTRIDE;
    int cell = w >> 5, wic = w & 31;
    if (wic >= 24) continue;
    int t0 = (int)((sqrtf(8.f * (float)cell + 9.f) - 3.f) * 0.5f + 0.5f);
    bool isDiag = false;
#pragma unroll
    for (int dt = -1; dt <= 1; ++dt) {
      int t = t0 + dt;
      if (t >= 0 && ((t * (t + 3)) >> 1) == cell) isDiag = true;
    }
    if (!isDiag) gstore(beta_g + idx, __uint_as_float(SENTU));
  }
  // ---- init global barrier (two-stage, r2-proven) ----
  __builtin_amdgcn_s_waitcnt(0);
  __syncthreads();
  if (tid == 0) {
    __hip_atomic_fetch_add(ibc, 1u, __ATOMIC_RELAXED, __HIP_MEMORY_SCOPE_AGENT);
    if (local == 0) {
      while (loadu(ibc) < 32u) __builtin_amdgcn_s_sleep(2);
      __hip_atomic_fetch_add(gcnt, 1u, __ATOMIC_RELAXED, __HIP_MEMORY_SCOPE_AGENT);
    }
    while (loadu(gcnt) < 16u) __builtin_amdgcn_s_sleep(2);
  }
  __syncthreads();

  // stage et into LDS as fp16 (row stride 584 halves); init aLOwn; betaOwn diag
  for (int i4 = tid; i4 < 3456; i4 += 256) {
    int f = i4 * 4;
    int x = f / 576, r = f - x * 576;
    float4 v = ((const float4*)et_g)[i4];
    h4 t; t.x = (h16)v.x; t.y = (h16)v.y; t.z = (h16)v.z; t.w = (h16)v.w;
    *(h4*)(et16h + x * 584 + r) = t;
  }
  for (int c = tid; c < 768; c += 256)
    aLOwn[c] = (local == 0 && c == 744) ? 0.f : NEGV;   // root aL(0,31)[n=0]=0
  if (tid < 24) betaOwn[tid] = gload(bbase + (size_t)tri(local, local) * 32 + tid);
  __syncthreads();

  //================ inside: levels 2..32-local, DATA-POLLED ================
  {
    float* eA   = (float*)(smem + O_EA);    // 744 f (exp'd left)
    float* eBf  = (float*)(smem + O_EBF);   // 744 f (right, raw)
    h16*  eb16  = (h16*)(smem + O_EB16);    // 744 h (right, exp'd fp16)
    h16*  rrh   = (h16*)(smem + O_RR);      // 576 h
    float* mrl  = (float*)(smem + O_MRL);   // 32
    float* scal = (float*)(smem + O_SCAL);  // 16
    const int lastLI = 32 - local;   // local=31 -> loop skipped
    for (int l = 2; l <= lastLI; l++) {
      int S = l - 1;
      int i = local, j = i + S, SN = S * 24;
      // A: poll+stage RIGHT column only (own row is betaOwn in LDS)
      for (int idx4 = tid; idx4 < 6 * S; idx4 += 256) {
        int s = idx4 / 6, q = idx4 - 6 * s;
        const float* cp = bbase + (size_t)tri(i + s + 1, j) * 32 + q * 4;
        float w0 = gload(cp), w1 = gload(cp + 1), w2 = gload(cp + 2), w3 = gload(cp + 3);
        while ((__float_as_uint(w0) == SENTU) | (__float_as_uint(w1) == SENTU) |
               (__float_as_uint(w2) == SENTU) | (__float_as_uint(w3) == SENTU)) {
          __builtin_amdgcn_s_sleep(1);
          w0 = gload(cp); w1 = gload(cp + 1); w2 = gload(cp + 2); w3 = gload(cp + 3);
        }
        float4 t4; t4.x = w0; t4.y = w1; t4.z = w2; t4.w = w3;
        ((float4*)eBf)[idx4] = t4;
      }
      __syncthreads();
      // B: per-s maxes + global M, wave 0 only (2 lanes per s)
      if (tid < 64) {
        int s = tid >> 1, h12 = tid & 1;
        float pa = NEGV, pb = NEGV;
        if (s < S) {
          const float4* ra = (const float4*)(betaOwn + s * 24 + h12 * 12);
          float4 A = ra[0], B = ra[1], C = ra[2];
          pa = MAX12(A, B, C);
          const float4* rb = (const float4*)(eBf + s * 24 + h12 * 12);
          float4 D = rb[0], E = rb[1], F = rb[2];
          pb = MAX12(D, E, F);
        }
        pa = fmaxf(pa, __shfl_xor(pa, 1));
        pb = fmaxf(pb, __shfl_xor(pb, 1));
        if (s < S && h12 == 0) mrl[s] = pb;
        float M0 = wmax64((s < S) ? pa + pb : NEGV);
        if (tid == 0) scal[0] = M0;
      }
      __syncthreads();
      // C: exp (left from betaOwn, right from eBf)
      float M = scal[0];
      for (int idx = tid; idx < SN; idx += 256) {
        int s = idx / 24;
        float m_ = mrl[s];
        eA[idx] = __expf(betaOwn[idx] + m_ - M);
        eb16[idx] = (h16)__expf(eBf[idx] - m_);
      }
      __syncthreads();
      // D: rank-1 rr[y][z] = sum_s eA[s][y]*eb16[s][z]
      if (tid < 144) {
        int y = tid / 6, zq = tid % 6;
        float4 acc = make_float4(0, 0, 0, 0);
        for (int s = 0; s < S; s++) {
          float a = eA[s * 24 + y];
          h4 b4 = ((const h4*)(eb16 + s * 24))[zq];
          acc.x = fmaf(a, (float)b4.x, acc.x); acc.y = fmaf(a, (float)b4.y, acc.y);
          acc.z = fmaf(a, (float)b4.z, acc.z); acc.w = fmaf(a, (float)b4.w, acc.w);
        }
        h4 t; t.x = (h16)acc.x; t.y = (h16)acc.y; t.z = (h16)acc.z; t.w = (h16)acc.w;
        ((h4*)(rrh + y * 24))[zq] = t;
      }
      __syncthreads();
      // E: matvec + writes (LDS betaOwn + global for neighbors); NO drain —
      // own reuse is LDS, neighbors poll the data word itself.
      if (tid < 48) {
        int x = tid >> 1, hh = tid & 1;
        const h4* ep = (const h4*)(et16h + x * 584 + hh * 288);
        const h4* rp = (const h4*)(rrh + hh * 288);
        float a2 = 0.f;
#pragma unroll 8
        for (int q = 0; q < 72; ++q) {
          h4 ev = ep[q], rv = rp[q];
          a2 = d2(ev.x, ev.y, rv.x, rv.y, a2);
          a2 = d2(ev.z, ev.w, rv.z, rv.w, a2);
        }
        a2 += __shfl_xor(a2, 1);
        if (hh == 0) {
          float val = M + __logf(fmaxf(a2, EPSV));
          betaOwn[S * 24 + x] = val;
          gstore(bbase + (size_t)tri(i, j) * 32 + x, val);
        }
      }
      __syncthreads();
    }
  }
  if (local == 0 && tid == 0) {
    gstore(logZg + b, betaOwn[744]);
    __builtin_amdgcn_s_waitcnt(0);
    __hip_atomic_fetch_add(done, 1u, __ATOMIC_RELAXED, __HIP_MEMORY_SCOPE_AGENT);
  }

  //================ outside: levels 32-local..2, neighbor-gated ================
  {
    float* ebL  = (float*)(smem + O_EA);    // 744 f (exp'd left)
    float* ebRf = (float*)(smem + O_EBF);   // 744 f (right, raw)
    h16*  eb16  = (h16*)(smem + O_EB16);    // 744 h (right, exp'd fp16)
    h16*  rrh   = (h16*)(smem + O_RR);      // 576 h (w, [y][z] fp16 for cL)
    float* wT   = (float*)(smem + O_WT);    // 600 f (w, [z][y*] f32 for cR)
    float* ea24 = (float*)(smem + O_EA24);  // 24 f
    float* mLs  = (float*)(smem + O_MRL);   // 32
    float* mRs  = (float*)(smem + O_MSM);   // 32
    float* scal = (float*)(smem + O_SCAL);  // 16
    const int lastLO = 32 - local;
    for (int l = lastLO; l >= 2; l--) {
      int S = l - 1;
      int i = local, j = i + S, SN = S * 24;
      // gate: left neighbor's cR of level l+1 done
      if (local > 0 && tid == 0) {
        unsigned need = (unsigned)(32 - l);
        while (loadu(slotO + local - 1) < need) __builtin_amdgcn_s_sleep(1);
      }
      __syncthreads();
      // A: wave0 = alpha read+prep (aL from LDS); waves1-3 = right-col staging
      if (tid < 64) {
        float av = NEGV;
        if (tid < 24)
          av = la2(aLOwn[S * 24 + tid], gload(aRb + tri(i, j) * 24 + tid));
        float mav = wmax64(av);
        if (tid < 24) ea24[tid] = __expf(av - mav);
        if (tid == 0) scal[0] = mav;
      } else {
        for (int idx4 = tid - 64; idx4 < 6 * S; idx4 += 192) {
          int s = idx4 / 6, q = idx4 - 6 * s;
          ((float4*)ebRf)[idx4] = ((const float4*)(bbase + (size_t)tri(i + s + 1, j) * 32))[q];
        }
      }
      __syncthreads();
      float ma = scal[0];
      // B: wave0 = per-s maxes (left from betaOwn); waves1-3 = w-compute
      if (tid < 64) {
        int s = tid >> 1, h12 = tid & 1;
        float pl = NEGV, pr = NEGV;
        if (s < S) {
          const float4* ra = (const float4*)(betaOwn + s * 24 + h12 * 12);
          float4 A = ra[0], B = ra[1], C = ra[2];
          pl = MAX12(A, B, C);
          const float4* rb = (const float4*)(ebRf + s * 24 + h12 * 12);
          float4 D = rb[0], E = rb[1], F = rb[2];
          pr = MAX12(D, E, F);
        }
        pl = fmaxf(pl, __shfl_xor(pl, 1));
        pr = fmaxf(pr, __shfl_xor(pr, 1));
        if (s < S && h12 == 0) { mLs[s] = pl; mRs[s] = pr; }
      } else if (tid < 208) {
        int t = tid - 64, y = t / 6, zq = t % 6;
        float4 acc = make_float4(0, 0, 0, 0);
#pragma unroll 4
        for (int x = 0; x < 24; x++) {
          float a = ea24[x];
          h4 ev = ((const h4*)(et16h + x * 584 + y * 24))[zq];
          acc.x = fmaf(a, (float)ev.x, acc.x); acc.y = fmaf(a, (float)ev.y, acc.y);
          acc.z = fmaf(a, (float)ev.z, acc.z); acc.w = fmaf(a, (float)ev.w, acc.w);
        }
        h4 t4; t4.x = (h16)acc.x; t4.y = (h16)acc.y; t4.z = (h16)acc.z; t4.w = (h16)acc.w;
        ((h4*)(rrh + y * 24))[zq] = t4;
        wT[(4 * zq + 0) * 25 + y] = acc.x;
        wT[(4 * zq + 1) * 25 + y] = acc.y;
        wT[(4 * zq + 2) * 25 + y] = acc.z;
        wT[(4 * zq + 3) * 25 + y] = acc.w;
      }
      __syncthreads();
      // C: exp (left from betaOwn)
      for (int idx = tid; idx < SN; idx += 256) {
        int s = idx / 24;
        ebL[idx] = __expf(betaOwn[idx] - mLs[s]);
        eb16[idx] = (h16)__expf(ebRf[idx] - mRs[s]);
      }
      __syncthreads();
      // D: cR -> aR[tri(i+s+1,j)][z] (chain-exclusive global RMW, f32 wT)
      for (int u = tid; u < SN; u += 256) {
        int s = u / 24, z = u - s * 24;
        const float* wz = wT + z * 25;
        const float* el = ebL + s * 24;
        float acc = 0;
#pragma unroll 4
        for (int y = 0; y < 24; y++) acc = fmaf(wz[y], el[y], acc);
        float val = __logf(fmaxf(acc, EPSV)) + ma + mLs[s];
        float* t = aRb + tri(i + s + 1, j) * 24 + z;
        gstore(t, la2(gload(t), val));
      }
      __builtin_amdgcn_s_waitcnt(0);
      __syncthreads();
      if (tid == 0) storeu(slotO + local, (unsigned)(33 - l));
      // E: cL -> aLOwn (pure LDS RMW; unique thread per element)
      for (int u = tid; u < SN; u += 256) {
        int s = u / 24, y = u - s * 24;
        const h4* w4 = (const h4*)(rrh + y * 24);
        const h4* r4 = (const h4*)(eb16 + s * 24);
        float acc = 0;
#pragma unroll
        for (int q = 0; q < 6; q++) {
          h4 a = w4[q], c4 = r4[q];
          acc = d2(a.x, a.y, c4.x, c4.y, acc);
          acc = d2(a.z, a.w, c4.z, c4.w, acc);
        }
        float val = __logf(fmaxf(acc, EPSV)) + ma + mRs[s];
        aLOwn[s * 24 + y] = la2(aLOwn[s * 24 + y], val);
      }
    }
    // publish aL diag (cell (i,i) = aLOwn row 0) + completion post
    __syncthreads();
    if (tid < 24) gstore(aLb + tri(local, local) * 24 + tid, aLOwn[tid]);
    __builtin_amdgcn_s_waitcnt(0);
    __syncthreads();
    if (tid == 0) storeu(slotO + local, 32u);
  }

  //================ mask logits + loss ================
  {
    int vbase = local * 1000;
    // prefetch pass-0 vocab (inputs — no gate needed)
    float pv0[24], pv1[24];
    {
      int o0 = tid, o1 = tid + 256;
      bool k0 = o0 < 1000, k1 = o1 < 1000;
#pragma unroll
      for (int n = 0; n < 24; n++) {
        pv0[n] = k0 ? vocab[n * 32000 + vbase + o0] : 0.f;
        pv1[n] = k1 ? vocab[n * 32000 + vbase + o1] : 0.f;
      }
    }
    // gate: all 32 column blocks of batch b fully finished (slotO[0..31] == 32)
    if (tid < 64) {
      for (;;) {
        unsigned v = 32;
        if (tid < 32) v = loadu(slotO + tid);
        if (__ballot(v >= 32u) == ~0ull) break;
        __builtin_amdgcn_s_sleep(1);
      }
    }
    __syncthreads();
    float* p = (float*)smem;  // 768 f, layout [n*32 + t] (overlays et16h — DP done)
    float logZv = gload(bbase + 496 * 32);
    for (int c = tid; c < 768; c += 256) {
      int n = c >> 5, t = c & 31;
      int dA = tri(t, t) * 24 + n;
      float al = gload(aLb + dA), ar = gload(aRb + dA);
      p[c] = __expf(la2(al, ar) + bbase[(size_t)tri(t, t) * 32 + n] - logZv);
    }
    __syncthreads();
    for (int pass = 0; pass < 2; pass++) {
      int o0 = tid + pass * 512, o1 = o0 + 256;
      bool v0ok = o0 < 1000, v1ok = o1 < 1000;
      int v0 = vbase + o0, v1 = vbase + o1;
      if (pass == 1) {
#pragma unroll
        for (int n = 0; n < 24; n++) {
          pv0[n] = v0ok ? vocab[n * 32000 + v0] : 0.f;
          pv1[n] = v1ok ? vocab[n * 32000 + v1] : 0.f;
        }
      }
      float* ob0 = out + (size_t)b * 32 * 32000 + v0;
      float* ob1 = out + (size_t)b * 32 * 32000 + v1;
      for (int t4 = 0; t4 < 32; t4 += 4) {
        float a00 = 1e-6f, a01 = 1e-6f, a02 = 1e-6f, a03 = 1e-6f;
        float a10 = 1e-6f, a11 = 1e-6f, a12 = 1e-6f, a13 = 1e-6f;
#pragma unroll 6
        for (int n = 0; n < 24; n++) {
          float4 pv = *(const float4*)(p + n * 32 + t4);
          a00 = fmaf(pv.x, pv0[n], a00); a01 = fmaf(pv.y, pv0[n], a01);
          a02 = fmaf(pv.z, pv0[n], a02); a03 = fmaf(pv.w, pv0[n], a03);
          a10 = fmaf(pv.x, pv1[n], a10); a11 = fmaf(pv.y, pv1[n], a11);
          a12 = fmaf(pv.z, pv1[n], a12); a13 = fmaf(pv.w, pv1[n], a13);
        }
        if (v0ok) {
          ob0[(size_t)(t4 + 0) * 32000] = __logf(a00);
          ob0[(size_t)(t4 + 1) * 32000] = __logf(a01);
          ob0[(size_t)(t4 + 2) * 32000] = __logf(a02);
          ob0[(size_t)(t4 + 3) * 32000] = __logf(a03);
        }
        if (v1ok) {
          ob1[(size_t)(t4 + 0) * 32000] = __logf(a10);
          ob1[(size_t)(t4 + 1) * 32000] = __logf(a11);
          ob1[(size_t)(t4 + 2) * 32000] = __logf(a12);
          ob1[(size_t)(t4 + 3) * 32000] = __logf(a13);
        }
      }
    }
    if (blk == 0 && tid == 0) {
      while (loadu(done) < 16u) __builtin_amdgcn_s_sleep(2);
      float s = 0;
      for (int q = 0; q < 16; q++) s += gload(logZg + q);
      out[16384000] = -s / 16.0f;
    }
  }
}

// ---------------------------------------------------------------- launch
extern "C" void kernel_launch(void* const* d_in, const int* in_sizes, int n_in,
                              void* d_out, int out_size, void* d_ws, size_t ws_size,
                              hipStream_t stream) {
  (void)in_sizes; (void)n_in; (void)out_size; (void)ws_size;
  const float* g_seq = (const float*)d_in[0];
  const float* Theta = (const float*)d_in[1];
  const float* vocab = (const float*)d_in[2];
  const float* lng   = (const float*)d_in[3];
  const float* lnb   = (const float*)d_in[4];
  const float* W1    = (const float*)d_in[5];
  const float* bb1   = (const float*)d_in[6];
  const float* W2    = (const float*)d_in[7];
  const float* bb2   = (const float*)d_in[8];
  float* out = (float*)d_out;

  float* ws = (float*)d_ws;
  unsigned* cnt = (unsigned*)d_ws;            // ws[0..2048) counters (memset 0)
  float* logZg  = ws + 2048;                  // 16
  float* et_g   = ws + 4096;                  // 13824
  float* beta_g = ws + 18432;                 // 16 * 16896 = 270336
  float* aL_g   = beta_g + 16 * BSTRIDE;      // 202752 (diag cells only)
  float* aR_g   = aL_g + 16 * ASTRIDE;        // 202752

  hipMemsetAsync(d_ws, 0, 8192, stream);

  void* args[] = {(void*)&g_seq, (void*)&Theta, (void*)&vocab, (void*)&lng,
                  (void*)&lnb, (void*)&W1, (void*)&bb1, (void*)&W2, (void*)&bb2,
                  (void*)&out, (void*)&et_g, (void*)&beta_g, (void*)&aL_g,
                  (void*)&aR_g, (void*)&cnt, (void*)&logZg};
  hipLaunchCooperativeKernel((const void*)mega_kernel, dim3(512), dim3(256),
                             args, 0, stream);
}

// Round 9
// 405.640 us; speedup vs baseline: 7.2737x; 1.0393x over previous
//
#include <hip/hip_runtime.h>
#include <math.h>

#define NEGV -1000000000.0f
#define EPSV 1e-38f
#define SENTU 0x7FC00001u

typedef _Float16 h16;
typedef _Float16 h2 __attribute__((ext_vector_type(2)));
typedef _Float16 h4 __attribute__((ext_vector_type(4)));
typedef _Float16 h8 __attribute__((ext_vector_type(8)));

constexpr int BSTRIDE = 528 * 32;   // beta floats per batch (128B-padded cells, write-once)
constexpr int ASTRIDE = 528 * 24;   // aL(diag-only)/aR floats per batch

// LDS layout (bytes from smem base); total 45616 (r8-identical)
constexpr int O_WK    = 28032;  // frontend scratch 1192 f (overlays betaOwn/aLOwn; frontend-only)
constexpr int O_BOWN  = 28032;  // betaOwn: 32 x 24 f (own beta row)
constexpr int O_ALOWN = 31104;  // aLOwn: 32 x 24 f (own aL row)
constexpr int O_EA    = 34176;  // eA / ebL: 744 f
constexpr int O_EBF   = 37152;  // eBf / ebRf: 744 f (raw right child)
constexpr int O_EB16  = 40128;  // exp'd right child: 744 h
constexpr int O_RR    = 41616;  // rr / w: 576 h (+pad)
constexpr int O_WT    = 42800;  // wT: 24 x 25 f (outside, [z][y] f32 mirror)
constexpr int O_EA24  = 45200;  // ea24: 24 f
constexpr int O_MRL   = 45296;  // 32 f (inside mrl / outside mLs)
constexpr int O_MSM   = 45424;  // 32 f (inside msm / outside mRs)
constexpr int O_SCAL  = 45552;  // 16 f
constexpr int SMEM_SZ = 45616;

__device__ __forceinline__ int tri(int i, int j) { return ((j * (j + 1)) >> 1) + i; }
__device__ __forceinline__ float la2(float a, float c) {
  float mx = fmaxf(a, c), mn = fminf(a, c);
  return mx + log1pf(__expf(mn - mx));
}
// relaxed agent-scope ops — bypass caches, hit the coherent point (r0/r2/r5/r7-proven)
__device__ __forceinline__ void gstore(float* p, float v) {
  __hip_atomic_store(p, v, __ATOMIC_RELAXED, __HIP_MEMORY_SCOPE_AGENT);
}
__device__ __forceinline__ float gload(const float* p) {
  return __hip_atomic_load(p, __ATOMIC_RELAXED, __HIP_MEMORY_SCOPE_AGENT);
}
__device__ __forceinline__ void storeu(unsigned* p, unsigned v) {
  __hip_atomic_store(p, v, __ATOMIC_RELAXED, __HIP_MEMORY_SCOPE_AGENT);
}
__device__ __forceinline__ unsigned loadu(const unsigned* p) {
  return __hip_atomic_load(p, __ATOMIC_RELAXED, __HIP_MEMORY_SCOPE_AGENT);
}
__device__ __forceinline__ void cfence() { asm volatile("" ::: "memory"); }
__device__ __forceinline__ float d2(h16 ax, h16 ay, h16 bx, h16 by, float c) {
#if __has_builtin(__builtin_amdgcn_fdot2)
  h2 a; a.x = ax; a.y = ay;
  h2 b; b.x = bx; b.y = by;
  return __builtin_amdgcn_fdot2(a, b, c, false);
#else
  return c + (float)ax * (float)bx + (float)ay * (float)by;
#endif
}
__device__ __forceinline__ float dot8(h8 a, h8 b, float c) {
  c = d2(a[0], a[1], b[0], b[1], c);
  c = d2(a[2], a[3], b[2], b[3], c);
  c = d2(a[4], a[5], b[4], b[5], c);
  c = d2(a[6], a[7], b[6], b[7], c);
  return c;
}
__device__ __forceinline__ float wmax64(float v) {
#pragma unroll
  for (int off = 32; off; off >>= 1) v = fmaxf(v, __shfl_xor(v, off));
  return v;
}

#define MAX4(A) fmaxf(fmaxf(A.x, A.y), fmaxf(A.z, A.w))
#define MAX12(A, B, C)                                                        \
  fmaxf(fmaxf(fmaxf(fmaxf(A.x, A.y), fmaxf(A.z, A.w)),                        \
              fmaxf(fmaxf(B.x, B.y), fmaxf(B.z, B.w))),                       \
        fmaxf(fmaxf(C.x, C.y), fmaxf(C.z, C.w)))

// 512 blocks x 256 threads, cooperative. b = blk&15, local = blk>>4.
// Inside sync: DATA-POLLING on sentinel-initialized beta cells (r7-proven).
// Outside sync: left-neighbor slotO chain, post after cR (r7-proven); gate
// poll hidden inside wave 0 (staging is gate-independent — cells final).
__global__ void __launch_bounds__(256, 2) mega_kernel(
    const float* __restrict__ g_seq, const float* __restrict__ Theta,
    const float* __restrict__ vocab, const float* __restrict__ lng,
    const float* __restrict__ lnb, const float* __restrict__ W1,
    const float* __restrict__ bb1, const float* __restrict__ W2,
    const float* __restrict__ bb2, float* __restrict__ out,
    float* __restrict__ et_g, float* __restrict__ beta_g,
    float* __restrict__ aL_g, float* __restrict__ aR_g,
    unsigned* __restrict__ cnt, float* __restrict__ logZg) {
  __shared__ __align__(16) unsigned char smem[SMEM_SZ];
  h16* et16h = (h16*)smem;              // 24 x 584 halves
  float* wk = (float*)(smem + O_WK);    // frontend scratch (1192 f)
  float* betaOwn = (float*)(smem + O_BOWN);  // [s][24]
  float* aLOwn   = (float*)(smem + O_ALOWN); // [s][24] (cell (i, i+s))
  const int tid = threadIdx.x;
  const int blk = blockIdx.x;
  const int b = blk & 15, local = blk >> 4;
  unsigned* gcnt  = cnt;                    // init stage-2 (16 arrivals)
  unsigned* done  = cnt + 8;                // logZ done count
  unsigned* ibc   = cnt + 16 + b * 16;      // init stage-1 per batch
  unsigned* slotO = cnt + 512 + b * 64 + 32;  // 32 outside progress words
  float* bbase = beta_g + b * BSTRIDE;
  float* aLb = aL_g + b * ASTRIDE;
  float* aRb = aR_g + b * ASTRIDE;

  //================ phase 0: frontend (task bt = blk) ================
  {
    float* g = wk;                       // 512
    float2* red = (float2*)(wk + 512);   // 512
    float* hb = wk + 1024;               // 128
    float* ob = wk + 1152;               // 32
    float* sc = wk + 1184;               // 8
    float2 raw = ((const float2*)(g_seq + (size_t)blk * 512))[tid];
    red[tid] = make_float2(raw.x + raw.y, raw.x * raw.x + raw.y * raw.y);
    __syncthreads();
    if (tid < 128) { float2 o = red[tid + 128], m = red[tid]; red[tid] = make_float2(m.x + o.x, m.y + o.y); }
    __syncthreads();
    if (tid < 64) {
      float2 v = red[tid], o = red[tid + 64];
      v.x += o.x; v.y += o.y;
      for (int off = 32; off; off >>= 1) { v.x += __shfl_xor(v.x, off); v.y += __shfl_xor(v.y, off); }
      if (tid == 0) {
        float mu = v.x / 512.0f;
        float var = v.y / 512.0f - mu * mu;
        sc[0] = mu; sc[1] = rsqrtf(var + 1e-5f);
      }
    }
    __syncthreads();
    float mu = sc[0], rstd = sc[1];
    g[2 * tid]     = (raw.x - mu) * rstd * lng[2 * tid]     + lnb[2 * tid];
    g[2 * tid + 1] = (raw.y - mu) * rstd * lng[2 * tid + 1] + lnb[2 * tid + 1];
    __syncthreads();
    {
      int j = tid & 127, hh = tid >> 7, c0 = hh * 256;
      float a0 = 0, a1 = 0, a2 = 0, a3 = 0;
      for (int c = 0; c < 256; c += 4) {
        a0 = fmaf(g[c0 + c],     W1[(c0 + c) * 128 + j],     a0);
        a1 = fmaf(g[c0 + c + 1], W1[(c0 + c + 1) * 128 + j], a1);
        a2 = fmaf(g[c0 + c + 2], W1[(c0 + c + 2) * 128 + j], a2);
        a3 = fmaf(g[c0 + c + 3], W1[(c0 + c + 3) * 128 + j], a3);
      }
      ((float*)red)[tid] = (a0 + a1) + (a2 + a3);
    }
    __syncthreads();
    if (tid < 128) {
      float a = ((float*)red)[tid] + ((float*)red)[tid + 128] + bb1[tid];
      hb[tid] = 0.5f * a * (1.0f + erff(a * 0.70710678118654752f));
    }
    __syncthreads();
    if (tid < 192) {
      int n = tid >> 3, q = tid & 7;
      float a = 0;
      for (int k = 0; k < 16; k++) a = fmaf(hb[q * 16 + k], W2[(q * 16 + k) * 24 + n], a);
      ((float*)red)[tid] = a;
    }
    __syncthreads();
    if (tid < 24) {
      float a = bb2[tid];
      for (int q = 0; q < 8; q++) a += ((float*)red)[tid * 8 + q];
      ob[tid] = a;
    }
    __syncthreads();
    if (tid == 0) {
      float m = ob[0];
      for (int n = 1; n < 24; n++) m = fmaxf(m, ob[n]);
      float s = 0;
      for (int n = 0; n < 24; n++) s += __expf(ob[n] - m);
      sc[2] = m + __logf(s);
    }
    __syncthreads();
    if (tid < 24) {
      int fb = blk >> 5, ft = blk & 31;
      gstore(beta_g + (size_t)fb * BSTRIDE + tri(ft, ft) * 32 + tid, ob[tid] - sc[2]);
    }
  }
  // theta rows (tm dropped — exact; et = exp(theta_log) <= 1)
  if (tid < 64) {
    int z = tid & 31;
    bool up = tid >= 32;
    int row = up ? (512 + blk) : blk;
    bool valid = (!up) || (blk < 64);
    float v = (z < 24 && valid) ? Theta[row * 24 + z] : NEGV;
    float m = v;
    for (int off = 16; off; off >>= 1) m = fmaxf(m, __shfl_xor(m, off));
    float e = (z < 24 && valid) ? __expf(v - m) : 0.f;
    float s = e;
    for (int off = 16; off; off >>= 1) s += __shfl_xor(s, off);
    float lse = m + __logf(s);
    if (z < 24 && valid) gstore(et_g + row * 24 + z, __expf(v - lse));
  }
  // aR init (all NEGV); aL is LDS-resident (only diags published at end)
  for (int idx = blk * 256 + tid; idx < 16 * ASTRIDE; idx += 131072)
    gstore(aR_g + idx, NEGV);
  // beta sentinel init: words 0..23 of every NON-diagonal cell
  for (int idx = blk * 256 + tid; idx < 16 * BSTRIDE; idx += 131072) {
    int w = idx % BSTRIDE;
    int cell = w >> 5, wic = w & 31;
    if (wic >= 24) continue;
    int t0 = (int)((sqrtf(8.f * (float)cell + 9.f) - 3.f) * 0.5f + 0.5f);
    bool isDiag = false;
#pragma unroll
    for (int dt = -1; dt <= 1; ++dt) {
      int t = t0 + dt;
      if (t >= 0 && ((t * (t + 3)) >> 1) == cell) isDiag = true;
    }
    if (!isDiag) gstore(beta_g + idx, __uint_as_float(SENTU));
  }
  // ---- init global barrier (two-stage, r2-proven) ----
  __builtin_amdgcn_s_waitcnt(0);
  __syncthreads();
  if (tid == 0) {
    __hip_atomic_fetch_add(ibc, 1u, __ATOMIC_RELAXED, __HIP_MEMORY_SCOPE_AGENT);
    if (local == 0) {
      while (loadu(ibc) < 32u) __builtin_amdgcn_s_sleep(2);
      __hip_atomic_fetch_add(gcnt, 1u, __ATOMIC_RELAXED, __HIP_MEMORY_SCOPE_AGENT);
    }
    while (loadu(gcnt) < 16u) __builtin_amdgcn_s_sleep(2);
  }
  __syncthreads();

  // stage et into LDS as fp16 (row stride 584 halves); init aLOwn; betaOwn diag
  for (int i4 = tid; i4 < 3456; i4 += 256) {
    int f = i4 * 4;
    int x = f / 576, r = f - x * 576;
    float4 v = ((const float4*)et_g)[i4];
    h4 t; t.x = (h16)v.x; t.y = (h16)v.y; t.z = (h16)v.z; t.w = (h16)v.w;
    *(h4*)(et16h + x * 584 + r) = t;
  }
  for (int c = tid; c < 768; c += 256)
    aLOwn[c] = (local == 0 && c == 744) ? 0.f : NEGV;   // root aL(0,31)[n=0]=0
  if (tid < 24) betaOwn[tid] = gload(bbase + (size_t)tri(local, local) * 32 + tid);
  __syncthreads();

  //================ inside: levels 2..32-local, DATA-POLLED ================
  {
    float* eA   = (float*)(smem + O_EA);    // 744 f (exp'd left)
    float* eBf  = (float*)(smem + O_EBF);   // 744 f (right, raw)
    h16*  eb16  = (h16*)(smem + O_EB16);    // 744 h (right, exp'd fp16)
    h16*  rrh   = (h16*)(smem + O_RR);      // 576 h
    float* mrl  = (float*)(smem + O_MRL);   // 32
    float* msm  = (float*)(smem + O_MSM);   // 32
    const int lastLI = 32 - local;   // local=31 -> loop skipped
    for (int l = 2; l <= lastLI; l++) {
      int S = l - 1;
      int i = local, j = i + S, SN = S * 24;
      // A: poll+stage RIGHT column, 8 lanes/s (q<6 active) + fused per-s maxes
      {
        int s = tid >> 3, q = tid & 7;
        float pa = NEGV, pb = NEGV;
        if (s < S && q < 6) {
          const float* cp = bbase + (size_t)tri(i + s + 1, j) * 32 + q * 4;
          float w0 = gload(cp), w1 = gload(cp + 1), w2 = gload(cp + 2), w3 = gload(cp + 3);
          while ((__float_as_uint(w0) == SENTU) | (__float_as_uint(w1) == SENTU) |
                 (__float_as_uint(w2) == SENTU) | (__float_as_uint(w3) == SENTU)) {
            __builtin_amdgcn_s_sleep(1);
            w0 = gload(cp); w1 = gload(cp + 1); w2 = gload(cp + 2); w3 = gload(cp + 3);
          }
          float4 t4; t4.x = w0; t4.y = w1; t4.z = w2; t4.w = w3;
          ((float4*)eBf)[s * 6 + q] = t4;
          pb = MAX4(t4);
          float4 oa = *(const float4*)(betaOwn + s * 24 + q * 4);
          pa = MAX4(oa);
        }
#pragma unroll
        for (int off = 1; off < 8; off <<= 1) {
          pa = fmaxf(pa, __shfl_xor(pa, off));
          pb = fmaxf(pb, __shfl_xor(pb, off));
        }
        if (q == 0) {
          mrl[s] = (s < S) ? pb : NEGV;
          msm[s] = (s < S) ? pa + pb : NEGV;
        }
      }
      __syncthreads();
      // C: per-thread M from broadcast msm reads, then exp
      float M;
      {
        const float4* mm = (const float4*)msm;
        float4 a0 = mm[0], a1 = mm[1], a2 = mm[2], a3 = mm[3];
        float4 a4 = mm[4], a5 = mm[5], a6 = mm[6], a7 = mm[7];
        M = fmaxf(fmaxf(fmaxf(MAX4(a0), MAX4(a1)), fmaxf(MAX4(a2), MAX4(a3))),
                  fmaxf(fmaxf(MAX4(a4), MAX4(a5)), fmaxf(MAX4(a6), MAX4(a7))));
      }
      for (int idx = tid; idx < SN; idx += 256) {
        int s = idx / 24;
        float m_ = mrl[s];
        eA[idx] = __expf(betaOwn[idx] + m_ - M);
        eb16[idx] = (h16)__expf(eBf[idx] - m_);
      }
      __syncthreads();
      // D: rank-1 rr[y][z] = sum_s eA[s][y]*eb16[s][z]
      if (tid < 144) {
        int y = tid / 6, zq = tid % 6;
        float4 acc = make_float4(0, 0, 0, 0);
        for (int s = 0; s < S; s++) {
          float a = eA[s * 24 + y];
          h4 b4 = ((const h4*)(eb16 + s * 24))[zq];
          acc.x = fmaf(a, (float)b4.x, acc.x); acc.y = fmaf(a, (float)b4.y, acc.y);
          acc.z = fmaf(a, (float)b4.z, acc.z); acc.w = fmaf(a, (float)b4.w, acc.w);
        }
        h4 t; t.x = (h16)acc.x; t.y = (h16)acc.y; t.z = (h16)acc.z; t.w = (h16)acc.w;
        ((h4*)(rrh + y * 24))[zq] = t;
      }
      __syncthreads();
      // E: matvec, 96 lanes (4 per x), h8 reads, 2-step shfl reduce
      if (tid < 96) {
        int x = tid >> 2, sub = tid & 3;
        const h8* ep = (const h8*)(et16h + x * 584 + sub * 144);
        const h8* rp = (const h8*)(rrh + sub * 144);
        float a2 = 0.f;
#pragma unroll 6
        for (int q = 0; q < 18; ++q) a2 = dot8(ep[q], rp[q], a2);
        a2 += __shfl_xor(a2, 1);
        a2 += __shfl_xor(a2, 2);
        if (sub == 0) {
          float val = M + __logf(fmaxf(a2, EPSV));
          betaOwn[S * 24 + x] = val;
          gstore(bbase + (size_t)tri(i, j) * 32 + x, val);
        }
      }
      __syncthreads();
    }
  }
  if (local == 0 && tid == 0) {
    gstore(logZg + b, betaOwn[744]);
    __builtin_amdgcn_s_waitcnt(0);
    __hip_atomic_fetch_add(done, 1u, __ATOMIC_RELAXED, __HIP_MEMORY_SCOPE_AGENT);
  }

  //================ outside: levels 32-local..2, neighbor-gated ================
  {
    float* ebL  = (float*)(smem + O_EA);    // 744 f (exp'd left)
    float* ebRf = (float*)(smem + O_EBF);   // 744 f (right, raw)
    h16*  eb16  = (h16*)(smem + O_EB16);    // 744 h (right, exp'd fp16)
    h16*  rrh   = (h16*)(smem + O_RR);      // 576 h (w, [y][z] fp16 for cL)
    float* wT   = (float*)(smem + O_WT);    // 600 f (w, [z][y*] f32 for cR)
    float* ea24 = (float*)(smem + O_EA24);  // 24 f
    float* mLs  = (float*)(smem + O_MRL);   // 32
    float* mRs  = (float*)(smem + O_MSM);   // 32
    float* scal = (float*)(smem + O_SCAL);  // 16
    const int lastLO = 32 - local;
    for (int l = lastLO; l >= 2; l--) {
      int S = l - 1;
      int i = local, j = i + S, SN = S * 24;
      // A: wave0 = {gate poll, alpha read+prep}; waves1-3 = right-col staging
      // (staging needs no gate: cells were verified final by own inside)
      if (tid < 64) {
        if (local > 0 && tid == 0) {
          unsigned need = (unsigned)(32 - l);
          while (loadu(slotO + local - 1) < need) __builtin_amdgcn_s_sleep(1);
        }
        cfence();
        float av = NEGV;
        if (tid < 24)
          av = la2(aLOwn[S * 24 + tid], gload(aRb + tri(i, j) * 24 + tid));
        float mav = wmax64(av);
        if (tid < 24) ea24[tid] = __expf(av - mav);
        if (tid == 0) scal[0] = mav;
      } else {
        for (int idx4 = tid - 64; idx4 < 6 * S; idx4 += 192) {
          int s = idx4 / 6, q = idx4 - 6 * s;
          ((float4*)ebRf)[idx4] = ((const float4*)(bbase + (size_t)tri(i + s + 1, j) * 32))[q];
        }
      }
      __syncthreads();
      float ma = scal[0];
      // B: wave0 = per-s maxes (left from betaOwn); waves1-3 = w-compute
      if (tid < 64) {
        int s = tid >> 1, h12 = tid & 1;
        float pl = NEGV, pr = NEGV;
        if (s < S) {
          const float4* ra = (const float4*)(betaOwn + s * 24 + h12 * 12);
          float4 A = ra[0], B = ra[1], C = ra[2];
          pl = MAX12(A, B, C);
          const float4* rb = (const float4*)(ebRf + s * 24 + h12 * 12);
          float4 D = rb[0], E = rb[1], F = rb[2];
          pr = MAX12(D, E, F);
        }
        pl = fmaxf(pl, __shfl_xor(pl, 1));
        pr = fmaxf(pr, __shfl_xor(pr, 1));
        if (s < S && h12 == 0) { mLs[s] = pl; mRs[s] = pr; }
      } else if (tid < 208) {
        int t = tid - 64, y = t / 6, zq = t % 6;
        float4 acc = make_float4(0, 0, 0, 0);
#pragma unroll 4
        for (int x = 0; x < 24; x++) {
          float a = ea24[x];
          h4 ev = ((const h4*)(et16h + x * 584 + y * 24))[zq];
          acc.x = fmaf(a, (float)ev.x, acc.x); acc.y = fmaf(a, (float)ev.y, acc.y);
          acc.z = fmaf(a, (float)ev.z, acc.z); acc.w = fmaf(a, (float)ev.w, acc.w);
        }
        h4 t4; t4.x = (h16)acc.x; t4.y = (h16)acc.y; t4.z = (h16)acc.z; t4.w = (h16)acc.w;
        ((h4*)(rrh + y * 24))[zq] = t4;
        wT[(4 * zq + 0) * 25 + y] = acc.x;
        wT[(4 * zq + 1) * 25 + y] = acc.y;
        wT[(4 * zq + 2) * 25 + y] = acc.z;
        wT[(4 * zq + 3) * 25 + y] = acc.w;
      }
      __syncthreads();
      // C: exp (left from betaOwn)
      for (int idx = tid; idx < SN; idx += 256) {
        int s = idx / 24;
        ebL[idx] = __expf(betaOwn[idx] - mLs[s]);
        eb16[idx] = (h16)__expf(ebRf[idx] - mRs[s]);
      }
      __syncthreads();
      // D: cR -> aR[tri(i+s+1,j)][z] (chain-exclusive global RMW, f32 wT)
      for (int u = tid; u < SN; u += 256) {
        int s = u / 24, z = u - s * 24;
        const float* wz = wT + z * 25;
        const float* el = ebL + s * 24;
        float acc = 0;
#pragma unroll 4
        for (int y = 0; y < 24; y++) acc = fmaf(wz[y], el[y], acc);
        float val = __logf(fmaxf(acc, EPSV)) + ma + mLs[s];
        float* t = aRb + tri(i + s + 1, j) * 24 + z;
        gstore(t, la2(gload(t), val));
      }
      __builtin_amdgcn_s_waitcnt(0);
      __syncthreads();
      if (tid == 0) storeu(slotO + local, (unsigned)(33 - l));
      // E: cL -> aLOwn (pure LDS RMW; unique thread per element), h8 reads
      for (int u = tid; u < SN; u += 256) {
        int s = u / 24, y = u - s * 24;
        const h8* w8 = (const h8*)(rrh + y * 24);
        const h8* r8 = (const h8*)(eb16 + s * 24);
        float acc = 0;
        acc = dot8(w8[0], r8[0], acc);
        acc = dot8(w8[1], r8[1], acc);
        acc = dot8(w8[2], r8[2], acc);
        float val = __logf(fmaxf(acc, EPSV)) + ma + mRs[s];
        aLOwn[s * 24 + y] = la2(aLOwn[s * 24 + y], val);
      }
    }
    // publish aL diag (cell (i,i) = aLOwn row 0) + completion post
    __syncthreads();
    if (tid < 24) gstore(aLb + tri(local, local) * 24 + tid, aLOwn[tid]);
    __builtin_amdgcn_s_waitcnt(0);
    __syncthreads();
    if (tid == 0) storeu(slotO + local, 32u);
  }

  //================ mask logits + loss ================
  {
    int vbase = local * 1000;
    // prefetch pass-0 vocab (inputs — no gate needed)
    float pv0[24], pv1[24];
    {
      int o0 = tid, o1 = tid + 256;
      bool k0 = o0 < 1000, k1 = o1 < 1000;
#pragma unroll
      for (int n = 0; n < 24; n++) {
        pv0[n] = k0 ? vocab[n * 32000 + vbase + o0] : 0.f;
        pv1[n] = k1 ? vocab[n * 32000 + vbase + o1] : 0.f;
      }
    }
    // gate: all 32 column blocks of batch b fully finished (slotO[0..31] == 32)
    if (tid < 64) {
      for (;;) {
        unsigned v = 32;
        if (tid < 32) v = loadu(slotO + tid);
        if (__ballot(v >= 32u) == ~0ull) break;
        __builtin_amdgcn_s_sleep(1);
      }
    }
    __syncthreads();
    float* p = (float*)smem;  // 768 f, layout [n*32 + t] (overlays et16h — DP done)
    float logZv = gload(bbase + 496 * 32);
    for (int c = tid; c < 768; c += 256) {
      int n = c >> 5, t = c & 31;
      int dA = tri(t, t) * 24 + n;
      float al = gload(aLb + dA), ar = gload(aRb + dA);
      p[c] = __expf(la2(al, ar) + bbase[(size_t)tri(t, t) * 32 + n] - logZv);
    }
    __syncthreads();
    for (int pass = 0; pass < 2; pass++) {
      int o0 = tid + pass * 512, o1 = o0 + 256;
      bool v0ok = o0 < 1000, v1ok = o1 < 1000;
      int v0 = vbase + o0, v1 = vbase + o1;
      if (pass == 1) {
#pragma unroll
        for (int n = 0; n < 24; n++) {
          pv0[n] = v0ok ? vocab[n * 32000 + v0] : 0.f;
          pv1[n] = v1ok ? vocab[n * 32000 + v1] : 0.f;
        }
      }
      float* ob0 = out + (size_t)b * 32 * 32000 + v0;
      float* ob1 = out + (size_t)b * 32 * 32000 + v1;
      for (int t4 = 0; t4 < 32; t4 += 4) {
        float a00 = 1e-6f, a01 = 1e-6f, a02 = 1e-6f, a03 = 1e-6f;
        float a10 = 1e-6f, a11 = 1e-6f, a12 = 1e-6f, a13 = 1e-6f;
#pragma unroll 6
        for (int n = 0; n < 24; n++) {
          float4 pv = *(const float4*)(p + n * 32 + t4);
          a00 = fmaf(pv.x, pv0[n], a00); a01 = fmaf(pv.y, pv0[n], a01);
          a02 = fmaf(pv.z, pv0[n], a02); a03 = fmaf(pv.w, pv0[n], a03);
          a10 = fmaf(pv.x, pv1[n], a10); a11 = fmaf(pv.y, pv1[n], a11);
          a12 = fmaf(pv.z, pv1[n], a12); a13 = fmaf(pv.w, pv1[n], a13);
        }
        if (v0ok) {
          ob0[(size_t)(t4 + 0) * 32000] = __logf(a00);
          ob0[(size_t)(t4 + 1) * 32000] = __logf(a01);
          ob0[(size_t)(t4 + 2) * 32000] = __logf(a02);
          ob0[(size_t)(t4 + 3) * 32000] = __logf(a03);
        }
        if (v1ok) {
          ob1[(size_t)(t4 + 0) * 32000] = __logf(a10);
          ob1[(size_t)(t4 + 1) * 32000] = __logf(a11);
          ob1[(size_t)(t4 + 2) * 32000] = __logf(a12);
          ob1[(size_t)(t4 + 3) * 32000] = __logf(a13);
        }
      }
    }
    if (blk == 0 && tid == 0) {
      while (loadu(done) < 16u) __builtin_amdgcn_s_sleep(2);
      float s = 0;
      for (int q = 0; q < 16; q++) s += gload(logZg + q);
      out[16384000] = -s / 16.0f;
    }
  }
}

// ---------------------------------------------------------------- launch
extern "C" void kernel_launch(void* const* d_in, const int* in_sizes, int n_in,
                              void* d_out, int out_size, void* d_ws, size_t ws_size,
                              hipStream_t stream) {
  (void)in_sizes; (void)n_in; (void)out_size; (void)ws_size;
  const float* g_seq = (const float*)d_in[0];
  const float* Theta = (const float*)d_in[1];
  const float* vocab = (const float*)d_in[2];
  const float* lng   = (const float*)d_in[3];
  const float* lnb   = (const float*)d_in[4];
  const float* W1    = (const float*)d_in[5];
  const float* bb1   = (const float*)d_in[6];
  const float* W2    = (const float*)d_in[7];
  const float* bb2   = (const float*)d_in[8];
  float* out = (float*)d_out;

  float* ws = (float*)d_ws;
  unsigned* cnt = (unsigned*)d_ws;            // ws[0..2048) counters (memset 0)
  float* logZg  = ws + 2048;                  // 16
  float* et_g   = ws + 4096;                  // 13824
  float* beta_g = ws + 18432;                 // 16 * 16896 = 270336
  float* aL_g   = beta_g + 16 * BSTRIDE;      // 202752 (diag cells only)
  float* aR_g   = aL_g + 16 * ASTRIDE;        // 202752

  hipMemsetAsync(d_ws, 0, 8192, stream);

  void* args[] = {(void*)&g_seq, (void*)&Theta, (void*)&vocab, (void*)&lng,
                  (void*)&lnb, (void*)&W1, (void*)&bb1, (void*)&W2, (void*)&bb2,
                  (void*)&out, (void*)&et_g, (void*)&beta_g, (void*)&aL_g,
                  (void*)&aR_g, (void*)&cnt, (void*)&logZg};
  hipLaunchCooperativeKernel((const void*)mega_kernel, dim3(512), dim3(256),
                             args, 0, stream);
}